// Round 1
// 6563.989 us; speedup vs baseline: 1.3184x; 1.3184x over previous
//
#include <hip/hip_runtime.h>
#include <math.h>

#define TID ((int)threadIdx.x)

static constexpr int Tn  = 1024;
static constexpr int Dn  = 128;
static constexpr int BNn = 256;
static constexpr long SL = 16777216;   // half-slot: 256*512*128 floats (64 MB)

// ---------------------------------------------------------------- utilities
__device__ __forceinline__ float wave_sum(float v) {
  v += __shfl_xor(v, 32); v += __shfl_xor(v, 16); v += __shfl_xor(v, 8);
  v += __shfl_xor(v, 4);  v += __shfl_xor(v, 2);  v += __shfl_xor(v, 1);
  return v;
}

// ---------------------------------------------------------------- K1: (B,T,N,D) -> (BN,T,D)
__global__ __launch_bounds__(256) void transpose_k(const float* __restrict__ z, float* __restrict__ zf) {
  long g = (long)blockIdx.x * 256 + TID;           // float4 index in zf
  int bn = (int)(g >> 15); int rem = (int)(g & 32767);
  int t = rem >> 5; int d4 = rem & 31;
  int b = bn >> 5, n = bn & 31;
  float4 v = ((const float4*)z)[(((long)b * Tn + t) * 32 + n) * 32 + d4];
  ((float4*)zf)[g] = v;
}

// ---------------------------------------------------------------- K2: 2-stage FFT (1024 = 32x32) + argmax + amp
// One block = one bn, 4 consecutive channels (one wave per channel).
// Stage1: A[t0,j] = sum_t1 z[t0+32t1] * W32^(t1 j)   (j=0..16 computed, 17..31 conj-mirrored)
// Stage2: X[k]    = sum_t0 W1024^(k t0) * A[t0, k&31], k=0..512, twiddle by rotation recurrence.
// Emits argmax f (lowest-index ties, identical to old packed-key atomicMax) and scaled amp.
__global__ __launch_bounds__(256) void fft_k(const float* __restrict__ zf,
                                             int* __restrict__ keyf,
                                             float* __restrict__ amp_re, float* __restrict__ amp_im) {
  int bn = blockIdx.x;
  int d0 = blockIdx.y * 4;
  __shared__ float2 ctab[1024];                    // (cos, sin)(2*pi*i/1024)
  __shared__ float zch[4][1024];
  __shared__ __align__(16) float Am[4][32][66];    // [ch][t0][2j interleaved re,im]; 66 = bank stagger
  const float astep = 6.1359231515425649e-3f;      // 2*pi/1024
  for (int i = TID; i < 1024; i += 256) {
    float ang = (float)i * astep;
    ctab[i] = make_float2(cosf(ang), sinf(ang));
  }
  for (int t = TID; t < 1024; t += 256) {
    float4 v = *(const float4*)(zf + ((long)bn * Tn + t) * Dn + d0);
    zch[0][t] = v.x; zch[1][t] = v.y; zch[2][t] = v.z; zch[3][t] = v.w;
  }
  __syncthreads();
  int lane = TID & 63, wv = TID >> 6;
  int t0 = lane & 31, hi = lane >> 5;
  // preload this lane's 32 z values (fixed t0, all t1)
  float zr[32];
  #pragma unroll
  for (int t1 = 0; t1 < 32; ++t1) zr[t1] = zch[wv][t0 + 32 * t1];
  // ---- stage 1
  for (int jj = 0; jj <= 8; ++jj) {
    int j = 2 * jj + hi;
    if (j <= 16) {
      float re = 0.f, im = 0.f;
      int stp = j << 5;                            // j*32: twiddle index step in 1024-table
      int idx = 0;
      #pragma unroll
      for (int t1 = 0; t1 < 32; ++t1) {
        float2 w = ctab[idx];                      // wave-uniform per half: LDS broadcast
        re += zr[t1] * w.x;
        im -= zr[t1] * w.y;
        idx = (idx + stp) & 1023;
      }
      *(float2*)&Am[wv][t0][2 * j] = make_float2(re, im);
      if (j >= 1 && j <= 15)
        *(float2*)&Am[wv][t0][2 * (32 - j)] = make_float2(re, -im);
    }
  }
  __syncthreads();
  // ---- stage 2: k = lane + 64*s
  unsigned long long bestkey = 0ULL;
  float bXR = 0.f, bXI = 0.f;
  for (int s = 0; s <= 8; ++s) {
    int k = lane + (s << 6);
    if (k <= 512) {
      int j = k & 31;
      float2 wk = ctab[k];                         // rotation by 2*pi*k/1024 per t0 step
      float c = 1.f, sn = 0.f, XR = 0.f, XI = 0.f;
      #pragma unroll
      for (int tb = 0; tb < 32; ++tb) {
        float2 a = *(float2*)&Am[wv][tb][2 * j];   // contiguous b64 across lanes: conflict-free
        XR += c * a.x + sn * a.y;
        XI += c * a.y - sn * a.x;
        float cn = c * wk.x - sn * wk.y;
        sn = sn * wk.x + c * wk.y;
        c = cn;
      }
      float m2 = XR * XR + XI * XI;
      unsigned long long key = ((unsigned long long)__float_as_uint(m2) << 32) | (unsigned)(1023 - k);
      if (key > bestkey) { bestkey = key; bXR = XR; bXI = XI; }
    }
  }
  // wave-level max over packed keys (ties -> lower f, same as old atomicMax scheme)
  #pragma unroll
  for (int off = 32; off >= 1; off >>= 1) {
    unsigned long long o = __shfl_xor(bestkey, off);
    if (o > bestkey) bestkey = o;
  }
  int fwin = 1023 - (int)(bestkey & 1023ULL);
  int owner = fwin & 63;                           // k = lane + 64*s  =>  owner lane = f & 63
  float XRw = __shfl(bXR, owner);
  float XIw = __shfl(bXI, owner);
  if (lane == 0) {
    float mag = sqrtf(XRw * XRw + XIw * XIw);
    float factor = mag / (mag + 1e-8f);
    float w = (fwin == 0 || fwin == 512) ? 1.f : 2.f;
    float sc = w * (1.f / 1024.f) * factor;
    int d = d0 + wv;
    amp_re[bn * 128 + d] = XRw * sc;
    amp_im[bn * 128 + d] = XIw * sc;
    keyf[bn * 128 + d] = fwin;
  }
}

// ---------------------------------------------------------------- K2c: z_rem = zf - z_sea
__global__ __launch_bounds__(256) void zrem_k(const float* __restrict__ zf,
                                              const int* __restrict__ keyf,
                                              const float* __restrict__ amp_re, const float* __restrict__ amp_im,
                                              float* __restrict__ z_rem) {
  __shared__ float tab[1024];
  for (int i = TID; i < 1024; i += 256) tab[i] = cosf((float)i * 6.1359231515425649e-3f);
  __syncthreads();
  long g = (long)blockIdx.x * 256 + TID;
  int bn = (int)(g >> 15); int rem = (int)(g & 32767);
  int t = rem >> 5; int d4 = (rem & 31) * 4;
  float4 zv = ((const float4*)zf)[g];
  float se[4];
  #pragma unroll
  for (int j = 0; j < 4; ++j) {
    int d = d4 + j;
    int f = keyf[bn * 128 + d];
    int idx = (f * t) & 1023;
    float cc = tab[idx], ss = tab[(idx + 768) & 1023];
    se[j] = amp_re[bn * 128 + d] * cc - amp_im[bn * 128 + d] * ss;
  }
  ((float4*)z_rem)[g] = make_float4(zv.x - se[0], zv.y - se[1], zv.z - se[2], zv.w - se[3]);
}

// ---------------------------------------------------------------- K3a: alpha (trend mix)
__global__ __launch_bounds__(256) void alpha_k(const float* __restrict__ z_rem,
                                               const float* __restrict__ Wq, const float* __restrict__ bq,
                                               float* __restrict__ alpha) {
  int bn = blockIdx.x;
  __shared__ float sm[128];
  __shared__ float lg[3];
  int d = TID & 127, half = TID >> 7;
  float s = 0.f;
  for (int t = half * 512; t < half * 512 + 512; ++t) s += z_rem[((long)bn * Tn + t) * Dn + d];
  if (!half) sm[d] = s;
  __syncthreads();
  if (half) sm[d] += s;
  __syncthreads();
  if (TID < 3) {
    float acc = 0.f;
    for (int dd = 0; dd < 128; ++dd) acc += sm[dd] * Wq[dd * 3 + TID];
    lg[TID] = acc * (1.f / 1024.f) + bq[TID];
  }
  __syncthreads();
  if (TID < 3) {
    float m = fmaxf(lg[0], fmaxf(lg[1], lg[2]));
    float e = expf(lg[TID] - m);
    float ssum = expf(lg[0] - m) + expf(lg[1] - m) + expf(lg[2] - m);
    alpha[bn * 3 + TID] = e / ssum;
  }
}

// ---------------------------------------------------------------- K3b: z_trend (7-tap conv)
__global__ __launch_bounds__(256) void trend_k(const float* __restrict__ z_rem,
                                               const float* __restrict__ alpha, float* __restrict__ z_trend) {
  long g = (long)blockIdx.x * 256 + TID;
  int bn = (int)(g >> 15); int rem = (int)(g & 32767);
  int t = rem >> 5; int c4 = (rem & 31) * 4;
  float a0 = alpha[bn * 3 + 0], a1 = alpha[bn * 3 + 1], a2 = alpha[bn * 3 + 2];
  float w1 = a0 * (1.f / 3.f) + a1 * (1.f / 5.f) + a2 * (1.f / 7.f);
  float w2 = a1 * (1.f / 5.f) + a2 * (1.f / 7.f);
  float w3 = a2 * (1.f / 7.f);
  float wj[7] = {w3, w2, w1, w1, w1, w2, w3};
  float ax = 0.f, ay = 0.f, az = 0.f, aw = 0.f;
  #pragma unroll
  for (int j = -3; j <= 3; ++j) {
    int tt = t + j;
    if (tt < 0 || tt >= Tn) continue;
    float4 v = *(const float4*)(z_rem + ((long)bn * Tn + tt) * Dn + c4);
    float w = wj[j + 3];
    ax += w * v.x; ay += w * v.y; az += w * v.z; aw += w * v.w;
  }
  ((float4*)z_trend)[g] = make_float4(ax, ay, az, aw);
}

// ---------------------------------------------------------------- generic f32 GEMM (N tile = 128)
enum { GM_PLAIN = 0, GM_FLAT = 1, GM_PMEAN = 2 };

template<int MODE>
__device__ __forceinline__ float4 a_load4(const float* __restrict__ A, int r, int k, int K, int Np, int p) {
  if (MODE == GM_PLAIN) {
    return *(const float4*)(A + (long)r * K + k);
  } else if (MODE == GM_FLAT) {
    int bn = r / Np; int np_ = r - bn * Np;
    int t = np_ * p + (k >> 7);
    if (t < Tn) return *(const float4*)(A + ((long)bn * Tn + t) * Dn + (k & 127));
    return make_float4(0.f, 0.f, 0.f, 0.f);
  } else {  // GM_PMEAN (K must be 128)
    int bn = r / Np; int np_ = r - bn * Np;
    int t0 = np_ * p;
    float4 sv = make_float4(0.f, 0.f, 0.f, 0.f);
    for (int j = 0; j < p; ++j) {
      int t = t0 + j;
      if (t < Tn) {
        float4 v = *(const float4*)(A + ((long)bn * Tn + t) * Dn + k);
        sv.x += v.x; sv.y += v.y; sv.z += v.z; sv.w += v.w;
      }
    }
    float inv = 1.f / (float)p;
    sv.x *= inv; sv.y *= inv; sv.z *= inv; sv.w *= inv;
    return sv;
  }
}

#define FMA_ROW(i, av) \
  acc[i][0] += (av) * bv.x; acc[i][1] += (av) * bv.y; acc[i][2] += (av) * bv.z; acc[i][3] += (av) * bv.w;

template<int MODE>
__global__ __launch_bounds__(256) void gemm_k(const float* __restrict__ A, const float* __restrict__ B,
                                              const float* __restrict__ bias, float* __restrict__ C,
                                              int M, int K, int ldb, int ldc, int Np, int p) {
  __shared__ float As[16][68];
  __shared__ float Bs[16][128];
  int r0 = blockIdx.x * 64;
  int colB = blockIdx.y * 128;
  float acc[8][4] = {{0}};
  int am = TID >> 2, ak = (TID & 3) * 4;
  int bk = TID >> 4, bc = (TID & 15) * 8;
  int tc = TID & 31, tr = TID >> 5;
  for (int k0 = 0; k0 < K; k0 += 16) {
    float4 av = a_load4<MODE>(A, r0 + am, k0 + ak, K, Np, p);
    float4 b0 = *(const float4*)(B + (long)(k0 + bk) * ldb + colB + bc);
    float4 b1 = *(const float4*)(B + (long)(k0 + bk) * ldb + colB + bc + 4);
    __syncthreads();
    As[ak + 0][am] = av.x; As[ak + 1][am] = av.y; As[ak + 2][am] = av.z; As[ak + 3][am] = av.w;
    *(float4*)&Bs[bk][bc] = b0; *(float4*)&Bs[bk][bc + 4] = b1;
    __syncthreads();
    #pragma unroll
    for (int kk = 0; kk < 16; ++kk) {
      float4 bv = *(float4*)&Bs[kk][tc * 4];
      float4 a0 = *(float4*)&As[kk][tr * 8];
      float4 a1 = *(float4*)&As[kk][tr * 8 + 4];
      FMA_ROW(0, a0.x) FMA_ROW(1, a0.y) FMA_ROW(2, a0.z) FMA_ROW(3, a0.w)
      FMA_ROW(4, a1.x) FMA_ROW(5, a1.y) FMA_ROW(6, a1.z) FMA_ROW(7, a1.w)
    }
  }
  float4 bb = make_float4(0.f, 0.f, 0.f, 0.f);
  if (bias) bb = *(const float4*)(bias + colB + tc * 4);
  #pragma unroll
  for (int i = 0; i < 8; ++i) {
    long r = r0 + tr * 8 + i;
    float4 o = make_float4(acc[i][0] + bb.x, acc[i][1] + bb.y, acc[i][2] + bb.z, acc[i][3] + bb.w);
    *(float4*)(C + r * (long)ldc + colB + tc * 4) = o;
  }
}

// ---------------------------------------------------------------- router: cat3 GEMM + gating + top3
// z_sea is NOT materialized: z_sea = zf - z_rem computed on the fly.
__global__ __launch_bounds__(256) void router_k(const float* __restrict__ zf, const float* __restrict__ z_rem,
                                                const float* __restrict__ z_trend,
                                                const float* __restrict__ Wf, const float* __restrict__ bf,
                                                const float* __restrict__ nfeat, const float* __restrict__ nlog,
                                                const float* __restrict__ Wr, const float* __restrict__ br,
                                                const float* __restrict__ Wn, const float* __restrict__ bnb,
                                                float* __restrict__ sparse) {
  __shared__ float As[16][68];
  __shared__ float Bs[16][128];
  __shared__ float Cs[64][132];
  __shared__ float wrn[128][8];
  __shared__ float lrow[64][4];
  long r0 = (long)blockIdx.x * 64;
  float acc[8][4] = {{0}};
  int am = TID >> 2, ak = (TID & 3) * 4;
  int bk = TID >> 4, bc = (TID & 15) * 8;
  int tc = TID & 31, tr = TID >> 5;
  for (int k0 = 0; k0 < 384; k0 += 16) {
    int k = k0 + ak;
    long row = (r0 + am) * 128;
    float4 av;
    if (k < 128) {
      av = *(const float4*)(zf + row + k);
    } else if (k < 256) {
      float4 a = *(const float4*)(zf + row + (k - 128));
      float4 b = *(const float4*)(z_rem + row + (k - 128));
      av = make_float4(a.x - b.x, a.y - b.y, a.z - b.z, a.w - b.w);
    } else {
      av = *(const float4*)(z_trend + row + (k - 256));
    }
    float4 b0 = *(const float4*)(Wf + (long)(k0 + bk) * 128 + bc);
    float4 b1 = *(const float4*)(Wf + (long)(k0 + bk) * 128 + bc + 4);
    __syncthreads();
    As[ak + 0][am] = av.x; As[ak + 1][am] = av.y; As[ak + 2][am] = av.z; As[ak + 3][am] = av.w;
    *(float4*)&Bs[bk][bc] = b0; *(float4*)&Bs[bk][bc + 4] = b1;
    __syncthreads();
    #pragma unroll
    for (int kk = 0; kk < 16; ++kk) {
      float4 bv = *(float4*)&Bs[kk][tc * 4];
      float4 a0 = *(float4*)&As[kk][tr * 8];
      float4 a1 = *(float4*)&As[kk][tr * 8 + 4];
      FMA_ROW(0, a0.x) FMA_ROW(1, a0.y) FMA_ROW(2, a0.z) FMA_ROW(3, a0.w)
      FMA_ROW(4, a1.x) FMA_ROW(5, a1.y) FMA_ROW(6, a1.z) FMA_ROW(7, a1.w)
    }
  }
  for (int idx = TID; idx < 128; idx += 256) {
    #pragma unroll
    for (int c = 0; c < 4; ++c) { wrn[idx][c] = Wr[idx * 4 + c]; wrn[idx][4 + c] = Wn[idx * 4 + c]; }
  }
  #pragma unroll
  for (int i = 0; i < 8; ++i) {
    long r = r0 + tr * 8 + i;
    float4 nfv = *(const float4*)(nfeat + r * 128 + tc * 4);
    Cs[tr * 8 + i][tc * 4 + 0] = acc[i][0] + bf[tc * 4 + 0] + 0.1f * nfv.x;
    Cs[tr * 8 + i][tc * 4 + 1] = acc[i][1] + bf[tc * 4 + 1] + 0.1f * nfv.y;
    Cs[tr * 8 + i][tc * 4 + 2] = acc[i][2] + bf[tc * 4 + 2] + 0.1f * nfv.z;
    Cs[tr * 8 + i][tc * 4 + 3] = acc[i][3] + bf[tc * 4 + 3] + 0.1f * nfv.w;
  }
  __syncthreads();
  int rr = TID >> 2, c = TID & 3;
  float la = 0.f, lb2 = 0.f;
  for (int d = 0; d < 128; ++d) {
    float g = Cs[rr][d];
    la += g * wrn[d][c]; lb2 += g * wrn[d][4 + c];
  }
  long r = r0 + rr;
  float x = lb2 + bnb[c];
  float sp = (x > 0.f) ? x + log1pf(expf(-x)) : log1pf(expf(x));
  float lg = la + br[c] + nlog[r * 4 + c] * sp;
  lrow[rr][c] = lg;
  __syncthreads();
  float l0 = lrow[rr][0], l1 = lrow[rr][1], l2 = lrow[rr][2], l3 = lrow[rr][3];
  float mx = fmaxf(fmaxf(l0, l1), fmaxf(l2, l3));
  float e0 = expf(l0 - mx), e1 = expf(l1 - mx), e2 = expf(l2 - mx), e3 = expf(l3 - mx);
  float s = e0 + e1 + e2 + e3;
  float r0v = e0 / s, r1v = e1 / s, r2v = e2 / s, r3v = e3 / s;
  // zero the min of rw; ties -> later index zeroed (matches top_k keeping lower index)
  int zi = 0; float mv = r0v;
  if (r1v <= mv) { mv = r1v; zi = 1; }
  if (r2v <= mv) { mv = r2v; zi = 2; }
  if (r3v <= mv) { mv = r3v; zi = 3; }
  float rwc = (c == 0) ? r0v : (c == 1) ? r1v : (c == 2) ? r2v : r3v;
  sparse[r * 4 + c] = (c == zi) ? 0.f : rwc;
}

// ---------------------------------------------------------------- per-branch combined local-attn weights
__global__ __launch_bounds__(256) void precompute_k(const float* __restrict__ lqkv_w,
                                                    const float* __restrict__ lqkv_b,
                                                    float* __restrict__ Wql, float* __restrict__ bql,
                                                    float* __restrict__ v1, float* __restrict__ c1) {
  int i = blockIdx.x;
  const float* lw0 = lqkv_w + (long)(i * 3 + 0) * 16384;
  const float* lw1 = lqkv_w + (long)(i * 3 + 1) * 16384;
  const float* lb0 = lqkv_b + (i * 3 + 0) * 128;
  const float* lb1 = lqkv_b + (i * 3 + 1) * 128;
  for (int idx = TID; idx < 16384; idx += 256) {
    int dp = idx >> 7, d = idx & 127;
    float s = 0.f;
    for (int e = 0; e < 128; ++e) s += lw0[dp * 128 + e] * lw1[d * 128 + e];
    Wql[(long)i * 16384 + idx] = s;
  }
  for (int d = TID; d < 128; d += 256) {
    float s = 0.f, s2 = 0.f;
    for (int e = 0; e < 128; ++e) { s += lb0[e] * lw1[d * 128 + e]; s2 += lw0[d * 128 + e] * lb1[e]; }
    bql[i * 128 + d] = s;
    v1[i * 128 + d] = s2;
  }
  if (TID == 0) {
    float s = 0.f;
    for (int e = 0; e < 128; ++e) s += lb0[e] * lb1[e];
    c1[i] = s;
  }
}

// ---------------------------------------------------------------- local attention -> pooled patches
__global__ __launch_bounds__(256) void local_attn(const float* __restrict__ zf, const float* __restrict__ w_vec,
                                                  const float* __restrict__ v1, const float* __restrict__ c1,
                                                  float* __restrict__ pooled, int Np, int p, int ibr) {
  int lane = TID & 63, wid = TID >> 6;
  int r = blockIdx.x * 4 + wid;
  int bn = r / Np, np_ = r - bn * Np;
  int d0 = lane, d1 = lane + 64;
  float wv0 = w_vec[(long)r * 128 + d0];
  float wv1 = w_vec[(long)r * 128 + d1];
  float p0[8], p1[8], sj[8];
  #pragma unroll
  for (int j = 0; j < 8; ++j) {
    p0[j] = 0.f; p1[j] = 0.f;
    if (j < p) {
      int t = np_ * p + j;
      if (t < Tn) {
        const float* src = zf + ((long)bn * Tn + t) * Dn;
        p0[j] = src[d0]; p1[j] = src[d1];
      }
    }
    float v = wv0 * p0[j] + wv1 * p1[j];
    sj[j] = wave_sum(v);
  }
  float pm0 = 0.f, pm1 = 0.f;
  #pragma unroll
  for (int j = 0; j < 8; ++j) if (j < p) { pm0 += p0[j]; pm1 += p1[j]; }
  float invp = 1.f / (float)p;
  pm0 *= invp; pm1 *= invp;
  float qb = wave_sum(pm0 * v1[ibr * 128 + d0] + pm1 * v1[ibr * 128 + d1]) + c1[ibr];
  const float scale = 0.08838834764831845f;
  float mx = -1e30f;
  #pragma unroll
  for (int j = 0; j < 8; ++j) if (j < p) { sj[j] = (sj[j] + qb) * scale; mx = fmaxf(mx, sj[j]); }
  float se = 0.f; float ej[8];
  #pragma unroll
  for (int j = 0; j < 8; ++j) { ej[j] = 0.f; if (j < p) { ej[j] = expf(sj[j] - mx); se += ej[j]; } }
  float inv = 1.f / se;
  float o0 = 0.f, o1 = 0.f;
  #pragma unroll
  for (int j = 0; j < 8; ++j) if (j < p) { float w = ej[j] * inv; o0 += w * p0[j]; o1 += w * p1[j]; }
  pooled[(long)r * 128 + d0] = o0;
  pooled[(long)r * 128 + d1] = o1;
}

// ---------------------------------------------------------------- global sigmoid-softmax attention (lo +=)
__global__ __launch_bounds__(256) void gattn_k(const float* __restrict__ gq, const float* __restrict__ gk,
                                               const float* __restrict__ gv, float* __restrict__ lo, int Np) {
  int mt = blockIdx.x, bn = blockIdx.y;
  int m0 = mt * 32;
  __shared__ float Q[32][132], Kt[32][132], Vt[32][132];
  __shared__ float W[32][33];
  __shared__ float denom[32];
  #pragma unroll
  for (int i = 0; i < 4; ++i) {
    int f4 = TID + 256 * i; int mm = f4 >> 5; int c4 = (f4 & 31) * 4;
    int m = m0 + mm;
    float4 v = (m < Np) ? *(const float4*)(gq + ((long)bn * Np + m) * 128 + c4) : make_float4(0.f, 0.f, 0.f, 0.f);
    *(float4*)&Q[mm][c4] = v;
  }
  if (TID < 32) denom[TID] = 0.f;
  float4 ac0 = make_float4(0.f, 0.f, 0.f, 0.f), ac1 = ac0, ac2 = ac0, ac3 = ac0;
  int mmS = TID >> 3, nnb = (TID & 7) * 4;
  int mb = TID >> 5, e4 = (TID & 31) * 4;
  const float scale = 0.08838834764831845f;
  for (int n0 = 0; n0 < Np; n0 += 32) {
    __syncthreads();
    #pragma unroll
    for (int i = 0; i < 4; ++i) {
      int f4 = TID + 256 * i; int nn = f4 >> 5; int c4 = (f4 & 31) * 4;
      int n = n0 + nn;
      float4 kv = (n < Np) ? *(const float4*)(gk + ((long)bn * Np + n) * 128 + c4) : make_float4(0.f, 0.f, 0.f, 0.f);
      float4 vv = (n < Np) ? *(const float4*)(gv + ((long)bn * Np + n) * 128 + c4) : make_float4(0.f, 0.f, 0.f, 0.f);
      *(float4*)&Kt[nn][c4] = kv;
      *(float4*)&Vt[nn][c4] = vv;
    }
    __syncthreads();
    float s0 = 0.f, s1 = 0.f, s2 = 0.f, s3 = 0.f;
    #pragma unroll 8
    for (int e = 0; e < 128; e += 4) {
      float4 q4 = *(float4*)&Q[mmS][e];
      float4 k0 = *(float4*)&Kt[nnb + 0][e];
      float4 k1 = *(float4*)&Kt[nnb + 1][e];
      float4 k2 = *(float4*)&Kt[nnb + 2][e];
      float4 k3 = *(float4*)&Kt[nnb + 3][e];
      s0 += q4.x * k0.x + q4.y * k0.y + q4.z * k0.z + q4.w * k0.w;
      s1 += q4.x * k1.x + q4.y * k1.y + q4.z * k1.z + q4.w * k1.w;
      s2 += q4.x * k2.x + q4.y * k2.y + q4.z * k2.z + q4.w * k2.w;
      s3 += q4.x * k3.x + q4.y * k3.y + q4.z * k3.z + q4.w * k3.w;
    }
    float sv[4] = {s0, s1, s2, s3};
    #pragma unroll
    for (int u = 0; u < 4; ++u) {
      int n = n0 + nnb + u;
      float w = 0.f;
      if (n < Np) {
        float sg = 1.f / (1.f + expf(-sv[u]));
        w = expf(sg * scale);
      }
      W[mmS][nnb + u] = w;
    }
    __syncthreads();
    if (TID < 32) {
      float dsum = 0.f;
      for (int nn = 0; nn < 32; ++nn) dsum += W[TID][nn];
      denom[TID] += dsum;
    }
    #pragma unroll 4
    for (int nn = 0; nn < 32; ++nn) {
      float4 v4 = *(float4*)&Vt[nn][e4];
      float w0 = W[mb][nn], w1 = W[mb + 8][nn], w2 = W[mb + 16][nn], w3 = W[mb + 24][nn];
      ac0.x += w0 * v4.x; ac0.y += w0 * v4.y; ac0.z += w0 * v4.z; ac0.w += w0 * v4.w;
      ac1.x += w1 * v4.x; ac1.y += w1 * v4.y; ac1.z += w1 * v4.z; ac1.w += w1 * v4.w;
      ac2.x += w2 * v4.x; ac2.y += w2 * v4.y; ac2.z += w2 * v4.z; ac2.w += w2 * v4.w;
      ac3.x += w3 * v4.x; ac3.y += w3 * v4.y; ac3.z += w3 * v4.z; ac3.w += w3 * v4.w;
    }
  }
  __syncthreads();
  #pragma unroll
  for (int kk2 = 0; kk2 < 4; ++kk2) {
    int m = m0 + mb + 8 * kk2;
    if (m < Np) {
      float inv = 1.f / denom[mb + 8 * kk2];
      float* lp = lo + ((long)bn * Np + m) * 128 + e4;
      float4 cur = *(float4*)lp;
      float4 a = (kk2 == 0) ? ac0 : (kk2 == 1) ? ac1 : (kk2 == 2) ? ac2 : ac3;
      cur.x += a.x * inv; cur.y += a.y * inv; cur.z += a.z * inv; cur.w += a.w * inv;
      *(float4*)lp = cur;
    }
  }
}

// ---------------------------------------------------------------- convT scatter + gate, DIRECT to out
// out_final[b, o*8 + t/128, n, t&127] += sparse[bn,t,i] * (up[bn,np,o,j] + cb[o])
__global__ __launch_bounds__(256) void scatter2_k(const float* __restrict__ up_t, const float* __restrict__ sparse,
                                                  const float* __restrict__ cb, float* __restrict__ out,
                                                  int Np, int p, int ibr) {
  int bn = blockIdx.x; int t0 = blockIdx.y * 128; int o0 = blockIdx.z * 16;
  __shared__ float tile[16][132];
  int np0 = t0 / p;
  int np1 = (t0 + 127) / p;
  if (np1 > Np - 1) np1 = Np - 1;
  int per = 16 * p;                    // contiguous floats per np_ in the o-tile
  int npi = 256 / per;                 // np_'s handled per iteration
  int sub = TID / per;
  int e   = TID - sub * per;
  int ol = e / p, j = e - ol * p;
  for (int npb = np0; npb <= np1; npb += npi) {
    int np_ = npb + sub;
    if (sub < npi && np_ <= np1) {
      int t = np_ * p + j;
      if (t >= t0 && t < t0 + 128 && t < Tn) {
        tile[ol][t - t0] = up_t[(((long)bn * Np + np_) * 128 + o0 + ol) * (long)p + j];
      }
    }
  }
  __syncthreads();
  int dd = TID & 127, ow = TID >> 7;
  int t = t0 + dd;
  float sp = sparse[((long)bn * 1024 + t) * 4 + ibr];
  int b = bn >> 5, n = bn & 31;
  int thi = t0 >> 7;
  for (int ol2 = ow; ol2 < 16; ol2 += 2) {
    int o = o0 + ol2;
    float v = sp * (tile[ol2][dd] + cb[o]);
    long idx = (((long)b * 1024 + o * 8 + thi) * 32 + n) * 128 + dd;
    out[idx] += v;
  }
}

// ---------------------------------------------------------------- launch
extern "C" void kernel_launch(void* const* d_in, const int* in_sizes, int n_in,
                              void* d_out, int out_size, void* d_ws, size_t ws_size,
                              hipStream_t stream) {
  const float* z      = (const float*)d_in[0];
  const float* nfeat  = (const float*)d_in[1];
  const float* nlog   = (const float*)d_in[2];
  const float* Wq_tr  = (const float*)d_in[3];
  const float* bq_tr  = (const float*)d_in[4];
  const float* Wf     = (const float*)d_in[5];
  const float* bf     = (const float*)d_in[6];
  const float* Wr     = (const float*)d_in[7];
  const float* br     = (const float*)d_in[8];
  const float* Wn     = (const float*)d_in[9];
  const float* bnb    = (const float*)d_in[10];
  const float* lqkv_w = (const float*)d_in[11];
  const float* lqkv_b = (const float*)d_in[12];
  const float* gqkvb  = (const float*)d_in[13];
  const float* proj_w = (const float*)d_in[14];
  const float* proj_b = (const float*)d_in[15];
  const float* conv_b = (const float*)d_in[16];
  const float* gqkv_w[4] = {(const float*)d_in[17], (const float*)d_in[19],
                            (const float*)d_in[21], (const float*)d_in[23]};
  const float* conv_w[4] = {(const float*)d_in[18], (const float*)d_in[20],
                            (const float*)d_in[22], (const float*)d_in[24]};
  float* out = (float*)d_out;
  float* ws = (float*)d_ws;

  // ---- workspace layout (floats)
  float* zf     = ws;                         // 33,554,432  (persistent)
  float* LOOP   = ws + 2 * SL;                // 67,108,864  (phase-aliased)
  float* sparse = ws + 6 * SL;                // 1,048,576
  int*   keyf   = (int*)(sparse + 1048576);   // 32,768 ints (reuses old keyb slot)
  float* amp_re = sparse + 1048576 + 65536;   // 32,768
  float* amp_im = amp_re + 32768;             // 32,768
  float* alpha  = amp_im + 32768;             // 1,024
  float* Wql    = alpha + 1024;               // 65,536
  float* bql    = Wql + 65536;                // 512
  float* v1     = bql + 512;                  // 512
  float* c1     = v1 + 512;                   // 64

  // pre-phase aliases inside LOOP
  float* z_rem   = LOOP;                      // 2 SL
  float* z_trend = LOOP + 2 * SL;             // 2 SL

  hipMemsetAsync(out, 0, (size_t)out_size * sizeof(float), stream);

  transpose_k<<<32768, 256, 0, stream>>>(z, zf);
  fft_k<<<dim3(256, 32), 256, 0, stream>>>(zf, keyf, amp_re, amp_im);
  zrem_k<<<32768, 256, 0, stream>>>(zf, keyf, amp_re, amp_im, z_rem);
  alpha_k<<<256, 256, 0, stream>>>(z_rem, Wq_tr, bq_tr, alpha);
  trend_k<<<32768, 256, 0, stream>>>(z_rem, alpha, z_trend);
  router_k<<<4096, 256, 0, stream>>>(zf, z_rem, z_trend, Wf, bf, nfeat, nlog, Wr, br, Wn, bnb, sparse);
  precompute_k<<<4, 256, 0, stream>>>(lqkv_w, lqkv_b, Wql, bql, v1, c1);

  const int PS[4]  = {2, 4, 6, 8};
  const int NPs[4] = {512, 256, 171, 128};
  for (int i = 0; i < 4; ++i) {
    int p = PS[i], Np = NPs[i];
    int M = BNn * Np;
    float* w_vec  = LOOP + 0 * SL;
    float* pooled = LOOP + 1 * SL;
    float* lob    = LOOP + 2 * SL;
    float* gqb    = LOOP + 0 * SL;
    float* gkb    = LOOP + 1 * SL;
    float* gvb    = LOOP + 3 * SL;
    float* fusedb = LOOP + 0 * SL;
    float* up_t   = LOOP + 1 * SL;
    long gsz = (long)p * 128 * 128;

    gemm_k<GM_PMEAN><<<dim3(M / 64, 1), 256, 0, stream>>>(zf, Wql + (long)i * 16384, bql + i * 128,
                                                          w_vec, M, 128, 128, 128, Np, p);
    local_attn<<<M / 4, 256, 0, stream>>>(zf, w_vec, v1, c1, pooled, Np, p, i);
    gemm_k<GM_PLAIN><<<dim3(M / 64, 1), 256, 0, stream>>>(pooled, lqkv_w + (long)(i * 3 + 2) * 16384,
                                                          lqkv_b + (i * 3 + 2) * 128, lob, M, 128, 128, 128, Np, p);
    gemm_k<GM_FLAT><<<dim3(M / 64, 1), 256, 0, stream>>>(zf, gqkv_w[i] + 0 * gsz, gqkvb + (i * 3 + 0) * 128,
                                                         gqb, M, p * 128, 128, 128, Np, p);
    gemm_k<GM_FLAT><<<dim3(M / 64, 1), 256, 0, stream>>>(zf, gqkv_w[i] + 1 * gsz, gqkvb + (i * 3 + 1) * 128,
                                                         gkb, M, p * 128, 128, 128, Np, p);
    gemm_k<GM_FLAT><<<dim3(M / 64, 1), 256, 0, stream>>>(zf, gqkv_w[i] + 2 * gsz, gqkvb + (i * 3 + 2) * 128,
                                                         gvb, M, p * 128, 128, 128, Np, p);
    gattn_k<<<dim3((Np + 31) / 32, 256), 256, 0, stream>>>(gqb, gkb, gvb, lob, Np);
    gemm_k<GM_PLAIN><<<dim3(M / 64, 1), 256, 0, stream>>>(lob, proj_w + (long)i * 16384, proj_b + i * 128,
                                                          fusedb, M, 128, 128, 128, Np, p);
    gemm_k<GM_PLAIN><<<dim3(M / 64, p), 256, 0, stream>>>(fusedb, conv_w[i], nullptr, up_t,
                                                          M, 128, 128 * p, 128 * p, Np, p);
    scatter2_k<<<dim3(256, 8, 8), 256, 0, stream>>>(up_t, sparse, conv_b + i * 128, out, Np, p, i);
  }
}

// Round 2
// 5321.774 us; speedup vs baseline: 1.6262x; 1.2334x over previous
//
#include <hip/hip_runtime.h>
#include <math.h>

#define TID ((int)threadIdx.x)

static constexpr int Tn  = 1024;
static constexpr int Dn  = 128;
static constexpr int BNn = 256;
static constexpr long SL = 16777216;   // half-slot: 256*512*128 floats (64 MB)

typedef __attribute__((ext_vector_type(8))) short s16x8;
typedef __attribute__((ext_vector_type(4))) float f32x4;

// ---------------------------------------------------------------- utilities
__device__ __forceinline__ float wave_sum(float v) {
  v += __shfl_xor(v, 32); v += __shfl_xor(v, 16); v += __shfl_xor(v, 8);
  v += __shfl_xor(v, 4);  v += __shfl_xor(v, 2);  v += __shfl_xor(v, 1);
  return v;
}

__device__ __forceinline__ unsigned short f2bf(float f) {   // RNE fp32->bf16
  unsigned u = __float_as_uint(f);
  return (unsigned short)((u + 0x7FFFu + ((u >> 16) & 1u)) >> 16);
}
__device__ __forceinline__ float bf2f(unsigned short s) {
  return __uint_as_float(((unsigned)s) << 16);
}

// ---------------------------------------------------------------- K1: (B,T,N,D) -> (BN,T,D)
__global__ __launch_bounds__(256) void transpose_k(const float* __restrict__ z, float* __restrict__ zf) {
  long g = (long)blockIdx.x * 256 + TID;           // float4 index in zf
  int bn = (int)(g >> 15); int rem = (int)(g & 32767);
  int t = rem >> 5; int d4 = rem & 31;
  int b = bn >> 5, n = bn & 31;
  float4 v = ((const float4*)z)[(((long)b * Tn + t) * 32 + n) * 32 + d4];
  ((float4*)zf)[g] = v;
}

// ---------------------------------------------------------------- K2: 2-stage FFT (1024 = 32x32) + argmax + amp
__global__ __launch_bounds__(256) void fft_k(const float* __restrict__ zf,
                                             int* __restrict__ keyf,
                                             float* __restrict__ amp_re, float* __restrict__ amp_im) {
  int bn = blockIdx.x;
  int d0 = blockIdx.y * 4;
  __shared__ float2 ctab[1024];                    // (cos, sin)(2*pi*i/1024)
  __shared__ float zch[4][1024];
  __shared__ __align__(16) float Am[4][32][66];    // [ch][t0][2j interleaved re,im]
  const float astep = 6.1359231515425649e-3f;      // 2*pi/1024
  for (int i = TID; i < 1024; i += 256) {
    float ang = (float)i * astep;
    ctab[i] = make_float2(cosf(ang), sinf(ang));
  }
  for (int t = TID; t < 1024; t += 256) {
    float4 v = *(const float4*)(zf + ((long)bn * Tn + t) * Dn + d0);
    zch[0][t] = v.x; zch[1][t] = v.y; zch[2][t] = v.z; zch[3][t] = v.w;
  }
  __syncthreads();
  int lane = TID & 63, wv = TID >> 6;
  int t0 = lane & 31, hi = lane >> 5;
  float zr[32];
  #pragma unroll
  for (int t1 = 0; t1 < 32; ++t1) zr[t1] = zch[wv][t0 + 32 * t1];
  // ---- stage 1
  for (int jj = 0; jj <= 8; ++jj) {
    int j = 2 * jj + hi;
    if (j <= 16) {
      float re = 0.f, im = 0.f;
      int stp = j << 5;
      int idx = 0;
      #pragma unroll
      for (int t1 = 0; t1 < 32; ++t1) {
        float2 w = ctab[idx];
        re += zr[t1] * w.x;
        im -= zr[t1] * w.y;
        idx = (idx + stp) & 1023;
      }
      *(float2*)&Am[wv][t0][2 * j] = make_float2(re, im);
      if (j >= 1 && j <= 15)
        *(float2*)&Am[wv][t0][2 * (32 - j)] = make_float2(re, -im);
    }
  }
  __syncthreads();
  // ---- stage 2
  unsigned long long bestkey = 0ULL;
  float bXR = 0.f, bXI = 0.f;
  for (int s = 0; s <= 8; ++s) {
    int k = lane + (s << 6);
    if (k <= 512) {
      int j = k & 31;
      float2 wk = ctab[k];
      float c = 1.f, sn = 0.f, XR = 0.f, XI = 0.f;
      #pragma unroll
      for (int tb = 0; tb < 32; ++tb) {
        float2 a = *(float2*)&Am[wv][tb][2 * j];
        XR += c * a.x + sn * a.y;
        XI += c * a.y - sn * a.x;
        float cn = c * wk.x - sn * wk.y;
        sn = sn * wk.x + c * wk.y;
        c = cn;
      }
      float m2 = XR * XR + XI * XI;
      unsigned long long key = ((unsigned long long)__float_as_uint(m2) << 32) | (unsigned)(1023 - k);
      if (key > bestkey) { bestkey = key; bXR = XR; bXI = XI; }
    }
  }
  #pragma unroll
  for (int off = 32; off >= 1; off >>= 1) {
    unsigned long long o = __shfl_xor(bestkey, off);
    if (o > bestkey) bestkey = o;
  }
  int fwin = 1023 - (int)(bestkey & 1023ULL);
  int owner = fwin & 63;
  float XRw = __shfl(bXR, owner);
  float XIw = __shfl(bXI, owner);
  if (lane == 0) {
    float mag = sqrtf(XRw * XRw + XIw * XIw);
    float factor = mag / (mag + 1e-8f);
    float w = (fwin == 0 || fwin == 512) ? 1.f : 2.f;
    float sc = w * (1.f / 1024.f) * factor;
    int d = d0 + wv;
    amp_re[bn * 128 + d] = XRw * sc;
    amp_im[bn * 128 + d] = XIw * sc;
    keyf[bn * 128 + d] = fwin;
  }
}

// ---------------------------------------------------------------- K2c: z_rem = zf - z_sea
__global__ __launch_bounds__(256) void zrem_k(const float* __restrict__ zf,
                                              const int* __restrict__ keyf,
                                              const float* __restrict__ amp_re, const float* __restrict__ amp_im,
                                              float* __restrict__ z_rem) {
  __shared__ float tab[1024];
  for (int i = TID; i < 1024; i += 256) tab[i] = cosf((float)i * 6.1359231515425649e-3f);
  __syncthreads();
  long g = (long)blockIdx.x * 256 + TID;
  int bn = (int)(g >> 15); int rem = (int)(g & 32767);
  int t = rem >> 5; int d4 = (rem & 31) * 4;
  float4 zv = ((const float4*)zf)[g];
  float se[4];
  #pragma unroll
  for (int j = 0; j < 4; ++j) {
    int d = d4 + j;
    int f = keyf[bn * 128 + d];
    int idx = (f * t) & 1023;
    float cc = tab[idx], ss = tab[(idx + 768) & 1023];
    se[j] = amp_re[bn * 128 + d] * cc - amp_im[bn * 128 + d] * ss;
  }
  ((float4*)z_rem)[g] = make_float4(zv.x - se[0], zv.y - se[1], zv.z - se[2], zv.w - se[3]);
}

// ---------------------------------------------------------------- K3a: alpha (trend mix)
__global__ __launch_bounds__(256) void alpha_k(const float* __restrict__ z_rem,
                                               const float* __restrict__ Wq, const float* __restrict__ bq,
                                               float* __restrict__ alpha) {
  int bn = blockIdx.x;
  __shared__ float sm[128];
  __shared__ float lg[3];
  int d = TID & 127, half = TID >> 7;
  float s = 0.f;
  for (int t = half * 512; t < half * 512 + 512; ++t) s += z_rem[((long)bn * Tn + t) * Dn + d];
  if (!half) sm[d] = s;
  __syncthreads();
  if (half) sm[d] += s;
  __syncthreads();
  if (TID < 3) {
    float acc = 0.f;
    for (int dd = 0; dd < 128; ++dd) acc += sm[dd] * Wq[dd * 3 + TID];
    lg[TID] = acc * (1.f / 1024.f) + bq[TID];
  }
  __syncthreads();
  if (TID < 3) {
    float m = fmaxf(lg[0], fmaxf(lg[1], lg[2]));
    float e = expf(lg[TID] - m);
    float ssum = expf(lg[0] - m) + expf(lg[1] - m) + expf(lg[2] - m);
    alpha[bn * 3 + TID] = e / ssum;
  }
}

// ---------------------------------------------------------------- K3b: z_trend (7-tap conv)
__global__ __launch_bounds__(256) void trend_k(const float* __restrict__ z_rem,
                                               const float* __restrict__ alpha, float* __restrict__ z_trend) {
  long g = (long)blockIdx.x * 256 + TID;
  int bn = (int)(g >> 15); int rem = (int)(g & 32767);
  int t = rem >> 5; int c4 = (rem & 31) * 4;
  float a0 = alpha[bn * 3 + 0], a1 = alpha[bn * 3 + 1], a2 = alpha[bn * 3 + 2];
  float w1 = a0 * (1.f / 3.f) + a1 * (1.f / 5.f) + a2 * (1.f / 7.f);
  float w2 = a1 * (1.f / 5.f) + a2 * (1.f / 7.f);
  float w3 = a2 * (1.f / 7.f);
  float wj[7] = {w3, w2, w1, w1, w1, w2, w3};
  float ax = 0.f, ay = 0.f, az = 0.f, aw = 0.f;
  #pragma unroll
  for (int j = -3; j <= 3; ++j) {
    int tt = t + j;
    if (tt < 0 || tt >= Tn) continue;
    float4 v = *(const float4*)(z_rem + ((long)bn * Tn + tt) * Dn + c4);
    float w = wj[j + 3];
    ax += w * v.x; ay += w * v.y; az += w * v.z; aw += w * v.w;
  }
  ((float4*)z_trend)[g] = make_float4(ax, ay, az, aw);
}

// ---------------------------------------------------------------- A-tile loaders (shared by fp32 + mfma gemms)
enum { GM_PLAIN = 0, GM_FLAT = 1, GM_PMEAN = 2 };

template<int MODE>
__device__ __forceinline__ float4 a_load4(const float* __restrict__ A, int r, int k, int K, int Np, int p) {
  if (MODE == GM_PLAIN) {
    return *(const float4*)(A + (long)r * K + k);
  } else if (MODE == GM_FLAT) {
    int bn = r / Np; int np_ = r - bn * Np;
    int t = np_ * p + (k >> 7);
    if (t < Tn) return *(const float4*)(A + ((long)bn * Tn + t) * Dn + (k & 127));
    return make_float4(0.f, 0.f, 0.f, 0.f);
  } else {  // GM_PMEAN (K must be 128)
    int bn = r / Np; int np_ = r - bn * Np;
    int t0 = np_ * p;
    float4 sv = make_float4(0.f, 0.f, 0.f, 0.f);
    for (int j = 0; j < p; ++j) {
      int t = t0 + j;
      if (t < Tn) {
        float4 v = *(const float4*)(A + ((long)bn * Tn + t) * Dn + k);
        sv.x += v.x; sv.y += v.y; sv.z += v.z; sv.w += v.w;
      }
    }
    float inv = 1.f / (float)p;
    sv.x *= inv; sv.y *= inv; sv.z *= inv; sv.w *= inv;
    return sv;
  }
}

#define FMA_ROW(i, av) \
  acc[i][0] += (av) * bv.x; acc[i][1] += (av) * bv.y; acc[i][2] += (av) * bv.z; acc[i][3] += (av) * bv.w;

// ---------------------------------------------------------------- fp32 GEMM (kept for conv stage only)
template<int MODE>
__global__ __launch_bounds__(256) void gemm_k(const float* __restrict__ A, const float* __restrict__ B,
                                              const float* __restrict__ bias, float* __restrict__ C,
                                              int M, int K, int ldb, int ldc, int Np, int p) {
  __shared__ float As[16][68];
  __shared__ float Bs[16][128];
  int r0 = blockIdx.x * 64;
  int colB = blockIdx.y * 128;
  float acc[8][4] = {{0}};
  int am = TID >> 2, ak = (TID & 3) * 4;
  int bk = TID >> 4, bc = (TID & 15) * 8;
  int tc = TID & 31, tr = TID >> 5;
  for (int k0 = 0; k0 < K; k0 += 16) {
    float4 av = a_load4<MODE>(A, r0 + am, k0 + ak, K, Np, p);
    float4 b0 = *(const float4*)(B + (long)(k0 + bk) * ldb + colB + bc);
    float4 b1 = *(const float4*)(B + (long)(k0 + bk) * ldb + colB + bc + 4);
    __syncthreads();
    As[ak + 0][am] = av.x; As[ak + 1][am] = av.y; As[ak + 2][am] = av.z; As[ak + 3][am] = av.w;
    *(float4*)&Bs[bk][bc] = b0; *(float4*)&Bs[bk][bc + 4] = b1;
    __syncthreads();
    #pragma unroll
    for (int kk = 0; kk < 16; ++kk) {
      float4 bv = *(float4*)&Bs[kk][tc * 4];
      float4 a0 = *(float4*)&As[kk][tr * 8];
      float4 a1 = *(float4*)&As[kk][tr * 8 + 4];
      FMA_ROW(0, a0.x) FMA_ROW(1, a0.y) FMA_ROW(2, a0.z) FMA_ROW(3, a0.w)
      FMA_ROW(4, a1.x) FMA_ROW(5, a1.y) FMA_ROW(6, a1.z) FMA_ROW(7, a1.w)
    }
  }
  float4 bb = make_float4(0.f, 0.f, 0.f, 0.f);
  if (bias) bb = *(const float4*)(bias + colB + tc * 4);
  #pragma unroll
  for (int i = 0; i < 8; ++i) {
    long r = r0 + tr * 8 + i;
    float4 o = make_float4(acc[i][0] + bb.x, acc[i][1] + bb.y, acc[i][2] + bb.z, acc[i][3] + bb.w);
    *(float4*)(C + r * (long)ldc + colB + tc * 4) = o;
  }
}

// ---------------------------------------------------------------- bf16 MFMA GEMM, 128x128 tile, BK=64
// BT: pre-transposed bf16 weights, row-major [Ntot][K].
// A: fp32, converted to bf16 (RNE) during LDS staging.
template<int MODE, int OUTB>
__global__ __launch_bounds__(256) void mgemm_k(const float* __restrict__ A,
                                               const unsigned short* __restrict__ BT,
                                               const float* __restrict__ bias, void* __restrict__ Cv,
                                               int M, int K, int ldc, int Np, int p) {
  __shared__ unsigned short As[128 * 72];   // rows padded to 72 bf16 (144B, 16B-aligned, 2-way max)
  __shared__ unsigned short Bs[128 * 72];
  int r0 = blockIdx.x * 128;
  int colB = blockIdx.y * 128;
  int wid = TID >> 6, lane = TID & 63;
  int wr = (wid >> 1) * 64, wc = (wid & 1) * 64;   // wave tile origin (64x64)
  int l15 = lane & 15, l4 = lane >> 4;
  f32x4 acc[4][4];
  f32x4 zero4 = {0.f, 0.f, 0.f, 0.f};
  #pragma unroll
  for (int a = 0; a < 4; ++a)
    #pragma unroll
    for (int b = 0; b < 4; ++b) acc[a][b] = zero4;
  int sr = TID >> 1, sh = (TID & 1) * 32;          // staging: row, k-half
  for (int k0 = 0; k0 < K; k0 += 64) {
    float4 av[8];
    #pragma unroll
    for (int j = 0; j < 8; ++j) av[j] = a_load4<MODE>(A, r0 + sr, k0 + sh + 4 * j, K, Np, p);
    s16x8 bv[4];
    const unsigned short* bsrc = BT + (long)(colB + sr) * K + k0 + sh;
    #pragma unroll
    for (int j = 0; j < 4; ++j) bv[j] = *(const s16x8*)(bsrc + 8 * j);
    __syncthreads();
    unsigned short* ar = As + sr * 72 + sh;
    #pragma unroll
    for (int j = 0; j < 8; ++j) {
      unsigned long long w =
        (unsigned long long)f2bf(av[j].x) | ((unsigned long long)f2bf(av[j].y) << 16) |
        ((unsigned long long)f2bf(av[j].z) << 32) | ((unsigned long long)f2bf(av[j].w) << 48);
      *(unsigned long long*)(ar + 4 * j) = w;
    }
    unsigned short* brr = Bs + sr * 72 + sh;
    #pragma unroll
    for (int j = 0; j < 4; ++j) *(s16x8*)(brr + 8 * j) = bv[j];
    __syncthreads();
    #pragma unroll
    for (int kk = 0; kk < 2; ++kk) {
      int kb = kk * 32 + l4 * 8;
      s16x8 af[4], bfr[4];
      #pragma unroll
      for (int mf = 0; mf < 4; ++mf) af[mf] = *(s16x8*)(As + (wr + mf * 16 + l15) * 72 + kb);
      #pragma unroll
      for (int nf = 0; nf < 4; ++nf) bfr[nf] = *(s16x8*)(Bs + (wc + nf * 16 + l15) * 72 + kb);
      #pragma unroll
      for (int mf = 0; mf < 4; ++mf)
        #pragma unroll
        for (int nf = 0; nf < 4; ++nf)
          acc[mf][nf] = __builtin_amdgcn_mfma_f32_16x16x32_bf16(af[mf], bfr[nf], acc[mf][nf], 0, 0, 0);
    }
  }
  // C/D layout (m89-verified): col = lane&15, row = (lane>>4)*4 + reg
  #pragma unroll
  for (int nf = 0; nf < 4; ++nf) {
    int col = colB + wc + nf * 16 + l15;
    float bb = bias ? bias[col] : 0.f;
    #pragma unroll
    for (int mf = 0; mf < 4; ++mf) {
      #pragma unroll
      for (int rg = 0; rg < 4; ++rg) {
        long row = r0 + wr + mf * 16 + l4 * 4 + rg;
        float v = acc[mf][nf][rg] + bb;
        if (OUTB) ((unsigned short*)Cv)[row * ldc + col] = f2bf(v);
        else      ((float*)Cv)[row * ldc + col] = v;
      }
    }
  }
}

// ---------------------------------------------------------------- build transposed bf16 weights
// 6 entries/branch: wql, lv, gq, gk, gv, proj. BT[n*K + k] = bf16(src[k*N + n]).
__global__ __launch_bounds__(256) void makebt_k(const float* __restrict__ Wql, const float* __restrict__ lqkv_w,
                                                const float* __restrict__ g0, const float* __restrict__ g1,
                                                const float* __restrict__ g2, const float* __restrict__ g3,
                                                const float* __restrict__ proj_w,
                                                unsigned short* __restrict__ dst) {
  int ent = blockIdx.y; int i = ent / 6, e = ent - i * 6;
  const int PS[4] = {2, 4, 6, 8};
  const long BOFF[4] = {0, 147456, 393216, 737280};   // 16384*(3+3p) cumsum
  int p = PS[i];
  const float* gw = (i == 0) ? g0 : (i == 1) ? g1 : (i == 2) ? g2 : g3;
  const float* src; int K, N; long doff = BOFF[i];
  if (e == 0)      { src = Wql + (long)i * 16384;              K = 128;     N = 128; }
  else if (e == 1) { src = lqkv_w + (long)(i * 3 + 2) * 16384; K = 128;     N = 128; doff += 16384; }
  else if (e <= 4) { src = gw + (long)(e - 2) * p * 16384;     K = p * 128; N = 128; doff += 32768 + (long)(e - 2) * p * 16384; }
  else             { src = proj_w + (long)i * 16384;           K = 128;     N = 128; doff += 32768 + 3L * p * 16384; }
  long tot = (long)K * N;
  long idx = (long)blockIdx.x * 256 + TID;
  if (idx >= tot) return;
  int n = (int)(idx / K), k = (int)(idx - (long)n * K);
  dst[doff + idx] = f2bf(src[(long)k * N + n]);
}

// ---------------------------------------------------------------- router: cat3 GEMM + gating + top3
__global__ __launch_bounds__(256) void router_k(const float* __restrict__ zf, const float* __restrict__ z_rem,
                                                const float* __restrict__ z_trend,
                                                const float* __restrict__ Wf, const float* __restrict__ bf,
                                                const float* __restrict__ nfeat, const float* __restrict__ nlog,
                                                const float* __restrict__ Wr, const float* __restrict__ br,
                                                const float* __restrict__ Wn, const float* __restrict__ bnb,
                                                float* __restrict__ sparse) {
  __shared__ float As[16][68];
  __shared__ float Bs[16][128];
  __shared__ float Cs[64][132];
  __shared__ float wrn[128][8];
  __shared__ float lrow[64][4];
  long r0 = (long)blockIdx.x * 64;
  float acc[8][4] = {{0}};
  int am = TID >> 2, ak = (TID & 3) * 4;
  int bk = TID >> 4, bc = (TID & 15) * 8;
  int tc = TID & 31, tr = TID >> 5;
  for (int k0 = 0; k0 < 384; k0 += 16) {
    int k = k0 + ak;
    long row = (r0 + am) * 128;
    float4 av;
    if (k < 128) {
      av = *(const float4*)(zf + row + k);
    } else if (k < 256) {
      float4 a = *(const float4*)(zf + row + (k - 128));
      float4 b = *(const float4*)(z_rem + row + (k - 128));
      av = make_float4(a.x - b.x, a.y - b.y, a.z - b.z, a.w - b.w);
    } else {
      av = *(const float4*)(z_trend + row + (k - 256));
    }
    float4 b0 = *(const float4*)(Wf + (long)(k0 + bk) * 128 + bc);
    float4 b1 = *(const float4*)(Wf + (long)(k0 + bk) * 128 + bc + 4);
    __syncthreads();
    As[ak + 0][am] = av.x; As[ak + 1][am] = av.y; As[ak + 2][am] = av.z; As[ak + 3][am] = av.w;
    *(float4*)&Bs[bk][bc] = b0; *(float4*)&Bs[bk][bc + 4] = b1;
    __syncthreads();
    #pragma unroll
    for (int kk = 0; kk < 16; ++kk) {
      float4 bv = *(float4*)&Bs[kk][tc * 4];
      float4 a0 = *(float4*)&As[kk][tr * 8];
      float4 a1 = *(float4*)&As[kk][tr * 8 + 4];
      FMA_ROW(0, a0.x) FMA_ROW(1, a0.y) FMA_ROW(2, a0.z) FMA_ROW(3, a0.w)
      FMA_ROW(4, a1.x) FMA_ROW(5, a1.y) FMA_ROW(6, a1.z) FMA_ROW(7, a1.w)
    }
  }
  for (int idx = TID; idx < 128; idx += 256) {
    #pragma unroll
    for (int c = 0; c < 4; ++c) { wrn[idx][c] = Wr[idx * 4 + c]; wrn[idx][4 + c] = Wn[idx * 4 + c]; }
  }
  #pragma unroll
  for (int i = 0; i < 8; ++i) {
    long r = r0 + tr * 8 + i;
    float4 nfv = *(const float4*)(nfeat + r * 128 + tc * 4);
    Cs[tr * 8 + i][tc * 4 + 0] = acc[i][0] + bf[tc * 4 + 0] + 0.1f * nfv.x;
    Cs[tr * 8 + i][tc * 4 + 1] = acc[i][1] + bf[tc * 4 + 1] + 0.1f * nfv.y;
    Cs[tr * 8 + i][tc * 4 + 2] = acc[i][2] + bf[tc * 4 + 2] + 0.1f * nfv.z;
    Cs[tr * 8 + i][tc * 4 + 3] = acc[i][3] + bf[tc * 4 + 3] + 0.1f * nfv.w;
  }
  __syncthreads();
  int rr = TID >> 2, c = TID & 3;
  float la = 0.f, lb2 = 0.f;
  for (int d = 0; d < 128; ++d) {
    float g = Cs[rr][d];
    la += g * wrn[d][c]; lb2 += g * wrn[d][4 + c];
  }
  long r = r0 + rr;
  float x = lb2 + bnb[c];
  float sp = (x > 0.f) ? x + log1pf(expf(-x)) : log1pf(expf(x));
  float lg = la + br[c] + nlog[r * 4 + c] * sp;
  lrow[rr][c] = lg;
  __syncthreads();
  float l0 = lrow[rr][0], l1 = lrow[rr][1], l2 = lrow[rr][2], l3 = lrow[rr][3];
  float mx = fmaxf(fmaxf(l0, l1), fmaxf(l2, l3));
  float e0 = expf(l0 - mx), e1 = expf(l1 - mx), e2 = expf(l2 - mx), e3 = expf(l3 - mx);
  float s = e0 + e1 + e2 + e3;
  float r0v = e0 / s, r1v = e1 / s, r2v = e2 / s, r3v = e3 / s;
  int zi = 0; float mv = r0v;
  if (r1v <= mv) { mv = r1v; zi = 1; }
  if (r2v <= mv) { mv = r2v; zi = 2; }
  if (r3v <= mv) { mv = r3v; zi = 3; }
  float rwc = (c == 0) ? r0v : (c == 1) ? r1v : (c == 2) ? r2v : r3v;
  sparse[r * 4 + c] = (c == zi) ? 0.f : rwc;
}

// ---------------------------------------------------------------- per-branch combined local-attn weights
__global__ __launch_bounds__(256) void precompute_k(const float* __restrict__ lqkv_w,
                                                    const float* __restrict__ lqkv_b,
                                                    float* __restrict__ Wql, float* __restrict__ bql,
                                                    float* __restrict__ v1, float* __restrict__ c1) {
  int i = blockIdx.x;
  const float* lw0 = lqkv_w + (long)(i * 3 + 0) * 16384;
  const float* lw1 = lqkv_w + (long)(i * 3 + 1) * 16384;
  const float* lb0 = lqkv_b + (i * 3 + 0) * 128;
  const float* lb1 = lqkv_b + (i * 3 + 1) * 128;
  for (int idx = TID; idx < 16384; idx += 256) {
    int dp = idx >> 7, d = idx & 127;
    float s = 0.f;
    for (int e = 0; e < 128; ++e) s += lw0[dp * 128 + e] * lw1[d * 128 + e];
    Wql[(long)i * 16384 + idx] = s;
  }
  for (int d = TID; d < 128; d += 256) {
    float s = 0.f, s2 = 0.f;
    for (int e = 0; e < 128; ++e) { s += lb0[e] * lw1[d * 128 + e]; s2 += lw0[d * 128 + e] * lb1[e]; }
    bql[i * 128 + d] = s;
    v1[i * 128 + d] = s2;
  }
  if (TID == 0) {
    float s = 0.f;
    for (int e = 0; e < 128; ++e) s += lb0[e] * lb1[e];
    c1[i] = s;
  }
}

// ---------------------------------------------------------------- local attention -> pooled patches
__global__ __launch_bounds__(256) void local_attn(const float* __restrict__ zf, const float* __restrict__ w_vec,
                                                  const float* __restrict__ v1, const float* __restrict__ c1,
                                                  float* __restrict__ pooled, int Np, int p, int ibr) {
  int lane = TID & 63, wid = TID >> 6;
  int r = blockIdx.x * 4 + wid;
  int bn = r / Np, np_ = r - bn * Np;
  int d0 = lane, d1 = lane + 64;
  float wv0 = w_vec[(long)r * 128 + d0];
  float wv1 = w_vec[(long)r * 128 + d1];
  float p0[8], p1[8], sj[8];
  #pragma unroll
  for (int j = 0; j < 8; ++j) {
    p0[j] = 0.f; p1[j] = 0.f;
    if (j < p) {
      int t = np_ * p + j;
      if (t < Tn) {
        const float* src = zf + ((long)bn * Tn + t) * Dn;
        p0[j] = src[d0]; p1[j] = src[d1];
      }
    }
    float v = wv0 * p0[j] + wv1 * p1[j];
    sj[j] = wave_sum(v);
  }
  float pm0 = 0.f, pm1 = 0.f;
  #pragma unroll
  for (int j = 0; j < 8; ++j) if (j < p) { pm0 += p0[j]; pm1 += p1[j]; }
  float invp = 1.f / (float)p;
  pm0 *= invp; pm1 *= invp;
  float qb = wave_sum(pm0 * v1[ibr * 128 + d0] + pm1 * v1[ibr * 128 + d1]) + c1[ibr];
  const float scale = 0.08838834764831845f;
  float mx = -1e30f;
  #pragma unroll
  for (int j = 0; j < 8; ++j) if (j < p) { sj[j] = (sj[j] + qb) * scale; mx = fmaxf(mx, sj[j]); }
  float se = 0.f; float ej[8];
  #pragma unroll
  for (int j = 0; j < 8; ++j) { ej[j] = 0.f; if (j < p) { ej[j] = expf(sj[j] - mx); se += ej[j]; } }
  float inv = 1.f / se;
  float o0 = 0.f, o1 = 0.f;
  #pragma unroll
  for (int j = 0; j < 8; ++j) if (j < p) { float w = ej[j] * inv; o0 += w * p0[j]; o1 += w * p1[j]; }
  pooled[(long)r * 128 + d0] = o0;
  pooled[(long)r * 128 + d1] = o1;
}

// ---------------------------------------------------------------- global sigmoid-softmax attention (lo +=), bf16 in
__global__ __launch_bounds__(256) void gattn_k(const unsigned short* __restrict__ gq,
                                               const unsigned short* __restrict__ gk,
                                               const unsigned short* __restrict__ gv,
                                               float* __restrict__ lo, int Np) {
  int mt = blockIdx.x, bn = blockIdx.y;
  int m0 = mt * 32;
  __shared__ float Q[32][132], Kt[32][132], Vt[32][132];
  __shared__ float W[32][36];
  __shared__ float denom[32];
  #pragma unroll
  for (int i = 0; i < 2; ++i) {
    int f8 = TID + 256 * i; int mm = f8 >> 4; int c8 = (f8 & 15) * 8;
    int m = m0 + mm;
    float4 q0 = make_float4(0.f, 0.f, 0.f, 0.f), q1 = q0;
    if (m < Np) {
      s16x8 qv = *(const s16x8*)(gq + ((long)bn * Np + m) * 128 + c8);
      q0 = make_float4(bf2f((unsigned short)qv[0]), bf2f((unsigned short)qv[1]),
                       bf2f((unsigned short)qv[2]), bf2f((unsigned short)qv[3]));
      q1 = make_float4(bf2f((unsigned short)qv[4]), bf2f((unsigned short)qv[5]),
                       bf2f((unsigned short)qv[6]), bf2f((unsigned short)qv[7]));
    }
    *(float4*)&Q[mm][c8] = q0; *(float4*)&Q[mm][c8 + 4] = q1;
  }
  if (TID < 32) denom[TID] = 0.f;
  float4 ac0 = make_float4(0.f, 0.f, 0.f, 0.f), ac1 = ac0, ac2 = ac0, ac3 = ac0;
  int mmS = TID >> 3, nb = TID & 7;                 // thread -> (row, col-group); cols nb+{0,8,16,24}
  int mb = TID >> 5, e4 = (TID & 31) * 4;
  const float scale = 0.08838834764831845f;
  for (int n0 = 0; n0 < Np; n0 += 32) {
    __syncthreads();
    #pragma unroll
    for (int i = 0; i < 2; ++i) {
      int f8 = TID + 256 * i; int nn = f8 >> 4; int c8 = (f8 & 15) * 8;
      int n = n0 + nn;
      float4 k0v = make_float4(0.f, 0.f, 0.f, 0.f), k1v = k0v, v0v = k0v, v1v = k0v;
      if (n < Np) {
        s16x8 kv = *(const s16x8*)(gk + ((long)bn * Np + n) * 128 + c8);
        s16x8 vv = *(const s16x8*)(gv + ((long)bn * Np + n) * 128 + c8);
        k0v = make_float4(bf2f((unsigned short)kv[0]), bf2f((unsigned short)kv[1]),
                          bf2f((unsigned short)kv[2]), bf2f((unsigned short)kv[3]));
        k1v = make_float4(bf2f((unsigned short)kv[4]), bf2f((unsigned short)kv[5]),
                          bf2f((unsigned short)kv[6]), bf2f((unsigned short)kv[7]));
        v0v = make_float4(bf2f((unsigned short)vv[0]), bf2f((unsigned short)vv[1]),
                          bf2f((unsigned short)vv[2]), bf2f((unsigned short)vv[3]));
        v1v = make_float4(bf2f((unsigned short)vv[4]), bf2f((unsigned short)vv[5]),
                          bf2f((unsigned short)vv[6]), bf2f((unsigned short)vv[7]));
      }
      *(float4*)&Kt[nn][c8] = k0v; *(float4*)&Kt[nn][c8 + 4] = k1v;
      *(float4*)&Vt[nn][c8] = v0v; *(float4*)&Vt[nn][c8 + 4] = v1v;
    }
    __syncthreads();
    float s0 = 0.f, s1 = 0.f, s2 = 0.f, s3 = 0.f;
    #pragma unroll 8
    for (int e = 0; e < 128; e += 4) {
      float4 q4 = *(float4*)&Q[mmS][e];
      float4 k0 = *(float4*)&Kt[nb + 0][e];
      float4 k1 = *(float4*)&Kt[nb + 8][e];
      float4 k2 = *(float4*)&Kt[nb + 16][e];
      float4 k3 = *(float4*)&Kt[nb + 24][e];
      s0 += q4.x * k0.x + q4.y * k0.y + q4.z * k0.z + q4.w * k0.w;
      s1 += q4.x * k1.x + q4.y * k1.y + q4.z * k1.z + q4.w * k1.w;
      s2 += q4.x * k2.x + q4.y * k2.y + q4.z * k2.z + q4.w * k2.w;
      s3 += q4.x * k3.x + q4.y * k3.y + q4.z * k3.z + q4.w * k3.w;
    }
    float sv[4] = {s0, s1, s2, s3};
    #pragma unroll
    for (int u = 0; u < 4; ++u) {
      int n = n0 + nb + 8 * u;
      float w = 0.f;
      if (n < Np) {
        float sg = 1.f / (1.f + expf(-sv[u]));
        w = expf(sg * scale);
      }
      W[mmS][nb + 8 * u] = w;
    }
    __syncthreads();
    if (TID < 32) {
      float dsum = 0.f;
      for (int nn = 0; nn < 32; ++nn) dsum += W[TID][nn];
      denom[TID] += dsum;
    }
    #pragma unroll 4
    for (int nn = 0; nn < 32; ++nn) {
      float4 v4 = *(float4*)&Vt[nn][e4];
      float w0 = W[mb][nn], w1 = W[mb + 8][nn], w2 = W[mb + 16][nn], w3 = W[mb + 24][nn];
      ac0.x += w0 * v4.x; ac0.y += w0 * v4.y; ac0.z += w0 * v4.z; ac0.w += w0 * v4.w;
      ac1.x += w1 * v4.x; ac1.y += w1 * v4.y; ac1.z += w1 * v4.z; ac1.w += w1 * v4.w;
      ac2.x += w2 * v4.x; ac2.y += w2 * v4.y; ac2.z += w2 * v4.z; ac2.w += w2 * v4.w;
      ac3.x += w3 * v4.x; ac3.y += w3 * v4.y; ac3.z += w3 * v4.z; ac3.w += w3 * v4.w;
    }
  }
  __syncthreads();
  #pragma unroll
  for (int kk2 = 0; kk2 < 4; ++kk2) {
    int m = m0 + mb + 8 * kk2;
    if (m < Np) {
      float inv = 1.f / denom[mb + 8 * kk2];
      float* lp = lo + ((long)bn * Np + m) * 128 + e4;
      float4 cur = *(float4*)lp;
      float4 a = (kk2 == 0) ? ac0 : (kk2 == 1) ? ac1 : (kk2 == 2) ? ac2 : ac3;
      cur.x += a.x * inv; cur.y += a.y * inv; cur.z += a.z * inv; cur.w += a.w * inv;
      *(float4*)lp = cur;
    }
  }
}

// ---------------------------------------------------------------- convT scatter + gate, DIRECT to out
__global__ __launch_bounds__(256) void scatter2_k(const float* __restrict__ up_t, const float* __restrict__ sparse,
                                                  const float* __restrict__ cb, float* __restrict__ out,
                                                  int Np, int p, int ibr) {
  int bn = blockIdx.x; int t0 = blockIdx.y * 128; int o0 = blockIdx.z * 16;
  __shared__ float tile[16][132];
  int np0 = t0 / p;
  int np1 = (t0 + 127) / p;
  if (np1 > Np - 1) np1 = Np - 1;
  int per = 16 * p;
  int npi = 256 / per;
  int sub = TID / per;
  int e   = TID - sub * per;
  int ol = e / p, j = e - ol * p;
  for (int npb = np0; npb <= np1; npb += npi) {
    int np_ = npb + sub;
    if (sub < npi && np_ <= np1) {
      int t = np_ * p + j;
      if (t >= t0 && t < t0 + 128 && t < Tn) {
        tile[ol][t - t0] = up_t[(((long)bn * Np + np_) * 128 + o0 + ol) * (long)p + j];
      }
    }
  }
  __syncthreads();
  int dd = TID & 127, ow = TID >> 7;
  int t = t0 + dd;
  float sp = sparse[((long)bn * 1024 + t) * 4 + ibr];
  int b = bn >> 5, n = bn & 31;
  int thi = t0 >> 7;
  for (int ol2 = ow; ol2 < 16; ol2 += 2) {
    int o = o0 + ol2;
    float v = sp * (tile[ol2][dd] + cb[o]);
    long idx = (((long)b * 1024 + o * 8 + thi) * 32 + n) * 128 + dd;
    out[idx] += v;
  }
}

// ---------------------------------------------------------------- launch
extern "C" void kernel_launch(void* const* d_in, const int* in_sizes, int n_in,
                              void* d_out, int out_size, void* d_ws, size_t ws_size,
                              hipStream_t stream) {
  const float* z      = (const float*)d_in[0];
  const float* nfeat  = (const float*)d_in[1];
  const float* nlog   = (const float*)d_in[2];
  const float* Wq_tr  = (const float*)d_in[3];
  const float* bq_tr  = (const float*)d_in[4];
  const float* Wf     = (const float*)d_in[5];
  const float* bf     = (const float*)d_in[6];
  const float* Wr     = (const float*)d_in[7];
  const float* br     = (const float*)d_in[8];
  const float* Wn     = (const float*)d_in[9];
  const float* bnb    = (const float*)d_in[10];
  const float* lqkv_w = (const float*)d_in[11];
  const float* lqkv_b = (const float*)d_in[12];
  const float* gqkvb  = (const float*)d_in[13];
  const float* proj_w = (const float*)d_in[14];
  const float* proj_b = (const float*)d_in[15];
  const float* conv_b = (const float*)d_in[16];
  const float* gqkv_w[4] = {(const float*)d_in[17], (const float*)d_in[19],
                            (const float*)d_in[21], (const float*)d_in[23]};
  const float* conv_w[4] = {(const float*)d_in[18], (const float*)d_in[20],
                            (const float*)d_in[22], (const float*)d_in[24]};
  float* out = (float*)d_out;
  float* ws = (float*)d_ws;

  // ---- workspace layout (floats)
  float* zf     = ws;                         // 2*SL (persistent)
  float* LOOP   = ws + 2 * SL;                // 4*SL (phase-aliased)
  float* sparse = ws + 6 * SL;                // 1,048,576
  int*   keyf   = (int*)(sparse + 1048576);   // 32,768 ints
  float* amp_re = sparse + 1048576 + 65536;   // 32,768
  float* amp_im = amp_re + 32768;             // 32,768
  float* alpha  = amp_im + 32768;             // 1,024
  float* Wql    = alpha + 1024;               // 65,536
  float* bql    = Wql + 65536;                // 512
  float* v1     = bql + 512;                  // 512
  float* c1     = v1 + 512;                   // 64
  // BT bf16 table lives in second half of s3 (ws+5.5SL); gv (bf16) uses exactly the
  // first half of s3; written after z_trend (s2+s3) is dead.
  unsigned short* BT = (unsigned short*)(ws + 5 * SL + SL / 2);   // 1,179,648 shorts

  // pre-phase aliases inside LOOP
  float* z_rem   = LOOP;                      // 2 SL
  float* z_trend = LOOP + 2 * SL;             // 2 SL

  hipMemsetAsync(out, 0, (size_t)out_size * sizeof(float), stream);

  transpose_k<<<32768, 256, 0, stream>>>(z, zf);
  fft_k<<<dim3(256, 32), 256, 0, stream>>>(zf, keyf, amp_re, amp_im);
  zrem_k<<<32768, 256, 0, stream>>>(zf, keyf, amp_re, amp_im, z_rem);
  alpha_k<<<256, 256, 0, stream>>>(z_rem, Wq_tr, bq_tr, alpha);
  trend_k<<<32768, 256, 0, stream>>>(z_rem, alpha, z_trend);
  router_k<<<4096, 256, 0, stream>>>(zf, z_rem, z_trend, Wf, bf, nfeat, nlog, Wr, br, Wn, bnb, sparse);
  precompute_k<<<4, 256, 0, stream>>>(lqkv_w, lqkv_b, Wql, bql, v1, c1);
  makebt_k<<<dim3(512, 24), 256, 0, stream>>>(Wql, lqkv_w, gqkv_w[0], gqkv_w[1], gqkv_w[2], gqkv_w[3],
                                              proj_w, BT);

  const int PS[4]   = {2, 4, 6, 8};
  const int NPs[4]  = {512, 256, 171, 128};
  const long BOFF[4] = {0, 147456, 393216, 737280};
  for (int i = 0; i < 4; ++i) {
    int p = PS[i], Np = NPs[i];
    int M = BNn * Np;
    float* w_vec  = LOOP + 0 * SL;
    float* pooled = LOOP + 1 * SL;
    float* lob    = LOOP + 2 * SL;
    unsigned short* gqb = (unsigned short*)(LOOP + 0 * SL);
    unsigned short* gkb = (unsigned short*)(LOOP + 1 * SL);
    unsigned short* gvb = (unsigned short*)(LOOP + 3 * SL);
    float* fusedb = LOOP + 0 * SL;
    float* up_t   = LOOP + 1 * SL;

    long bo = BOFF[i];
    const unsigned short* bt_wql  = BT + bo;
    const unsigned short* bt_lv   = BT + bo + 16384;
    const unsigned short* bt_g0   = BT + bo + 32768;
    const unsigned short* bt_g1   = bt_g0 + (long)p * 16384;
    const unsigned short* bt_g2   = bt_g1 + (long)p * 16384;
    const unsigned short* bt_proj = bt_g0 + 3L * p * 16384;

    mgemm_k<GM_PMEAN, 0><<<dim3(M / 128, 1), 256, 0, stream>>>(zf, bt_wql, bql + i * 128,
                                                               w_vec, M, 128, 128, Np, p);
    local_attn<<<M / 4, 256, 0, stream>>>(zf, w_vec, v1, c1, pooled, Np, p, i);
    mgemm_k<GM_PLAIN, 0><<<dim3(M / 128, 1), 256, 0, stream>>>(pooled, bt_lv, lqkv_b + (i * 3 + 2) * 128,
                                                               lob, M, 128, 128, Np, p);
    mgemm_k<GM_FLAT, 1><<<dim3(M / 128, 1), 256, 0, stream>>>(zf, bt_g0, gqkvb + (i * 3 + 0) * 128,
                                                              gqb, M, p * 128, 128, Np, p);
    mgemm_k<GM_FLAT, 1><<<dim3(M / 128, 1), 256, 0, stream>>>(zf, bt_g1, gqkvb + (i * 3 + 1) * 128,
                                                              gkb, M, p * 128, 128, Np, p);
    mgemm_k<GM_FLAT, 1><<<dim3(M / 128, 1), 256, 0, stream>>>(zf, bt_g2, gqkvb + (i * 3 + 2) * 128,
                                                              gvb, M, p * 128, 128, Np, p);
    gattn_k<<<dim3((Np + 31) / 32, 256), 256, 0, stream>>>(gqb, gkb, gvb, lob, Np);
    mgemm_k<GM_PLAIN, 0><<<dim3(M / 128, 1), 256, 0, stream>>>(lob, bt_proj, proj_b + i * 128,
                                                               fusedb, M, 128, 128, Np, p);
    // conv stays fp32: last stage before output, keeps absmax headroom
    gemm_k<GM_PLAIN><<<dim3(M / 64, p), 256, 0, stream>>>(fusedb, conv_w[i], nullptr, up_t,
                                                          M, 128, 128 * p, 128 * p, Np, p);
    scatter2_k<<<dim3(256, 8, 8), 256, 0, stream>>>(up_t, sparse, conv_b + i * 128, out, Np, p, i);
  }
}

// Round 3
// 4283.633 us; speedup vs baseline: 2.0202x; 1.2424x over previous
//
#include <hip/hip_runtime.h>
#include <math.h>

#define TID ((int)threadIdx.x)

static constexpr int Tn  = 1024;
static constexpr int Dn  = 128;
static constexpr int BNn = 256;
static constexpr long SL = 16777216;   // half-slot: 256*512*128 floats (64 MB)

typedef __attribute__((ext_vector_type(8))) short s16x8;
typedef __attribute__((ext_vector_type(4))) float f32x4;

// ---------------------------------------------------------------- utilities
__device__ __forceinline__ float wave_sum(float v) {
  v += __shfl_xor(v, 32); v += __shfl_xor(v, 16); v += __shfl_xor(v, 8);
  v += __shfl_xor(v, 4);  v += __shfl_xor(v, 2);  v += __shfl_xor(v, 1);
  return v;
}

__device__ __forceinline__ unsigned short f2bf(float f) {   // RNE fp32->bf16
  unsigned u = __float_as_uint(f);
  return (unsigned short)((u + 0x7FFFu + ((u >> 16) & 1u)) >> 16);
}
__device__ __forceinline__ float bf2f(unsigned short s) {
  return __uint_as_float(((unsigned)s) << 16);
}

// ---------------------------------------------------------------- K1: (B,T,N,D) -> (BN,T,D)
__global__ __launch_bounds__(256) void transpose_k(const float* __restrict__ z, float* __restrict__ zf) {
  long g = (long)blockIdx.x * 256 + TID;           // float4 index in zf
  int bn = (int)(g >> 15); int rem = (int)(g & 32767);
  int t = rem >> 5; int d4 = rem & 31;
  int b = bn >> 5, n = bn & 31;
  float4 v = ((const float4*)z)[(((long)b * Tn + t) * 32 + n) * 32 + d4];
  ((float4*)zf)[g] = v;
}

// ---------------------------------------------------------------- K2: 2-stage FFT (1024 = 32x32) + argmax + amp
__global__ __launch_bounds__(256) void fft_k(const float* __restrict__ zf,
                                             int* __restrict__ keyf,
                                             float* __restrict__ amp_re, float* __restrict__ amp_im) {
  int bn = blockIdx.x;
  int d0 = blockIdx.y * 4;
  __shared__ float2 ctab[1024];                    // (cos, sin)(2*pi*i/1024)
  __shared__ float zch[4][1024];
  __shared__ __align__(16) float Am[4][32][66];    // [ch][t0][2j interleaved re,im]
  const float astep = 6.1359231515425649e-3f;      // 2*pi/1024
  for (int i = TID; i < 1024; i += 256) {
    float ang = (float)i * astep;
    ctab[i] = make_float2(cosf(ang), sinf(ang));
  }
  for (int t = TID; t < 1024; t += 256) {
    float4 v = *(const float4*)(zf + ((long)bn * Tn + t) * Dn + d0);
    zch[0][t] = v.x; zch[1][t] = v.y; zch[2][t] = v.z; zch[3][t] = v.w;
  }
  __syncthreads();
  int lane = TID & 63, wv = TID >> 6;
  int t0 = lane & 31, hi = lane >> 5;
  float zr[32];
  #pragma unroll
  for (int t1 = 0; t1 < 32; ++t1) zr[t1] = zch[wv][t0 + 32 * t1];
  // ---- stage 1
  for (int jj = 0; jj <= 8; ++jj) {
    int j = 2 * jj + hi;
    if (j <= 16) {
      float re = 0.f, im = 0.f;
      int stp = j << 5;
      int idx = 0;
      #pragma unroll
      for (int t1 = 0; t1 < 32; ++t1) {
        float2 w = ctab[idx];
        re += zr[t1] * w.x;
        im -= zr[t1] * w.y;
        idx = (idx + stp) & 1023;
      }
      *(float2*)&Am[wv][t0][2 * j] = make_float2(re, im);
      if (j >= 1 && j <= 15)
        *(float2*)&Am[wv][t0][2 * (32 - j)] = make_float2(re, -im);
    }
  }
  __syncthreads();
  // ---- stage 2
  unsigned long long bestkey = 0ULL;
  float bXR = 0.f, bXI = 0.f;
  for (int s = 0; s <= 8; ++s) {
    int k = lane + (s << 6);
    if (k <= 512) {
      int j = k & 31;
      float2 wk = ctab[k];
      float c = 1.f, sn = 0.f, XR = 0.f, XI = 0.f;
      #pragma unroll
      for (int tb = 0; tb < 32; ++tb) {
        float2 a = *(float2*)&Am[wv][tb][2 * j];
        XR += c * a.x + sn * a.y;
        XI += c * a.y - sn * a.x;
        float cn = c * wk.x - sn * wk.y;
        sn = sn * wk.x + c * wk.y;
        c = cn;
      }
      float m2 = XR * XR + XI * XI;
      unsigned long long key = ((unsigned long long)__float_as_uint(m2) << 32) | (unsigned)(1023 - k);
      if (key > bestkey) { bestkey = key; bXR = XR; bXI = XI; }
    }
  }
  #pragma unroll
  for (int off = 32; off >= 1; off >>= 1) {
    unsigned long long o = __shfl_xor(bestkey, off);
    if (o > bestkey) bestkey = o;
  }
  int fwin = 1023 - (int)(bestkey & 1023ULL);
  int owner = fwin & 63;
  float XRw = __shfl(bXR, owner);
  float XIw = __shfl(bXI, owner);
  if (lane == 0) {
    float mag = sqrtf(XRw * XRw + XIw * XIw);
    float factor = mag / (mag + 1e-8f);
    float w = (fwin == 0 || fwin == 512) ? 1.f : 2.f;
    float sc = w * (1.f / 1024.f) * factor;
    int d = d0 + wv;
    amp_re[bn * 128 + d] = XRw * sc;
    amp_im[bn * 128 + d] = XIw * sc;
    keyf[bn * 128 + d] = fwin;
  }
}

// ---------------------------------------------------------------- K2c: z_rem = zf - z_sea
__global__ __launch_bounds__(256) void zrem_k(const float* __restrict__ zf,
                                              const int* __restrict__ keyf,
                                              const float* __restrict__ amp_re, const float* __restrict__ amp_im,
                                              float* __restrict__ z_rem) {
  __shared__ float tab[1024];
  for (int i = TID; i < 1024; i += 256) tab[i] = cosf((float)i * 6.1359231515425649e-3f);
  __syncthreads();
  long g = (long)blockIdx.x * 256 + TID;
  int bn = (int)(g >> 15); int rem = (int)(g & 32767);
  int t = rem >> 5; int d4 = (rem & 31) * 4;
  float4 zv = ((const float4*)zf)[g];
  float se[4];
  #pragma unroll
  for (int j = 0; j < 4; ++j) {
    int d = d4 + j;
    int f = keyf[bn * 128 + d];
    int idx = (f * t) & 1023;
    float cc = tab[idx], ss = tab[(idx + 768) & 1023];
    se[j] = amp_re[bn * 128 + d] * cc - amp_im[bn * 128 + d] * ss;
  }
  ((float4*)z_rem)[g] = make_float4(zv.x - se[0], zv.y - se[1], zv.z - se[2], zv.w - se[3]);
}

// ---------------------------------------------------------------- K3a: alpha (trend mix)
__global__ __launch_bounds__(256) void alpha_k(const float* __restrict__ z_rem,
                                               const float* __restrict__ Wq, const float* __restrict__ bq,
                                               float* __restrict__ alpha) {
  int bn = blockIdx.x;
  __shared__ float sm[128];
  __shared__ float lg[3];
  int d = TID & 127, half = TID >> 7;
  float s = 0.f;
  for (int t = half * 512; t < half * 512 + 512; ++t) s += z_rem[((long)bn * Tn + t) * Dn + d];
  if (!half) sm[d] = s;
  __syncthreads();
  if (half) sm[d] += s;
  __syncthreads();
  if (TID < 3) {
    float acc = 0.f;
    for (int dd = 0; dd < 128; ++dd) acc += sm[dd] * Wq[dd * 3 + TID];
    lg[TID] = acc * (1.f / 1024.f) + bq[TID];
  }
  __syncthreads();
  if (TID < 3) {
    float m = fmaxf(lg[0], fmaxf(lg[1], lg[2]));
    float e = expf(lg[TID] - m);
    float ssum = expf(lg[0] - m) + expf(lg[1] - m) + expf(lg[2] - m);
    alpha[bn * 3 + TID] = e / ssum;
  }
}

// ---------------------------------------------------------------- K3b: z_trend (7-tap conv)
__global__ __launch_bounds__(256) void trend_k(const float* __restrict__ z_rem,
                                               const float* __restrict__ alpha, float* __restrict__ z_trend) {
  long g = (long)blockIdx.x * 256 + TID;
  int bn = (int)(g >> 15); int rem = (int)(g & 32767);
  int t = rem >> 5; int c4 = (rem & 31) * 4;
  float a0 = alpha[bn * 3 + 0], a1 = alpha[bn * 3 + 1], a2 = alpha[bn * 3 + 2];
  float w1 = a0 * (1.f / 3.f) + a1 * (1.f / 5.f) + a2 * (1.f / 7.f);
  float w2 = a1 * (1.f / 5.f) + a2 * (1.f / 7.f);
  float w3 = a2 * (1.f / 7.f);
  float wj[7] = {w3, w2, w1, w1, w1, w2, w3};
  float ax = 0.f, ay = 0.f, az = 0.f, aw = 0.f;
  #pragma unroll
  for (int j = -3; j <= 3; ++j) {
    int tt = t + j;
    if (tt < 0 || tt >= Tn) continue;
    float4 v = *(const float4*)(z_rem + ((long)bn * Tn + tt) * Dn + c4);
    float w = wj[j + 3];
    ax += w * v.x; ay += w * v.y; az += w * v.z; aw += w * v.w;
  }
  ((float4*)z_trend)[g] = make_float4(ax, ay, az, aw);
}

// ---------------------------------------------------------------- A-tile loaders
enum { GM_PLAIN = 0, GM_FLAT = 1, GM_PMEAN = 2 };

template<int MODE>
__device__ __forceinline__ float4 a_load4(const float* __restrict__ A, int r, int k, int K, int Np, int p) {
  if (MODE == GM_PLAIN) {
    return *(const float4*)(A + (long)r * K + k);
  } else if (MODE == GM_FLAT) {
    int bn = r / Np; int np_ = r - bn * Np;
    int t = np_ * p + (k >> 7);
    if (t < Tn) return *(const float4*)(A + ((long)bn * Tn + t) * Dn + (k & 127));
    return make_float4(0.f, 0.f, 0.f, 0.f);
  } else {  // GM_PMEAN (K must be 128)
    int bn = r / Np; int np_ = r - bn * Np;
    int t0 = np_ * p;
    float4 sv = make_float4(0.f, 0.f, 0.f, 0.f);
    for (int j = 0; j < p; ++j) {
      int t = t0 + j;
      if (t < Tn) {
        float4 v = *(const float4*)(A + ((long)bn * Tn + t) * Dn + k);
        sv.x += v.x; sv.y += v.y; sv.z += v.z; sv.w += v.w;
      }
    }
    float inv = 1.f / (float)p;
    sv.x *= inv; sv.y *= inv; sv.z *= inv; sv.w *= inv;
    return sv;
  }
}

#define FMA_ROW(i, av) \
  acc[i][0] += (av) * bv.x; acc[i][1] += (av) * bv.y; acc[i][2] += (av) * bv.z; acc[i][3] += (av) * bv.w;

// ---------------------------------------------------------------- bf16 MFMA GEMM, 128x128 tile, BK=64
// BT: pre-transposed bf16 weights, row-major [Ntot][K].
// OUTB: 0 = fp32 row-major, 1 = bf16 row-major, 2 = bf16 transposed (gvT[bn][col][np], ldc=NpT)
template<int MODE, int OUTB>
__global__ __launch_bounds__(256) void mgemm_k(const float* __restrict__ A,
                                               const unsigned short* __restrict__ BT,
                                               const float* __restrict__ bias, void* __restrict__ Cv,
                                               int M, int K, int ldc, int Np, int p) {
  __shared__ unsigned short As[128 * 72];   // rows padded to 72 bf16
  __shared__ unsigned short Bs[128 * 72];
  int r0 = blockIdx.x * 128;
  int colB = blockIdx.y * 128;
  int wid = TID >> 6, lane = TID & 63;
  int wr = (wid >> 1) * 64, wc = (wid & 1) * 64;   // wave tile origin (64x64)
  int l15 = lane & 15, l4 = lane >> 4;
  f32x4 acc[4][4];
  f32x4 zero4 = {0.f, 0.f, 0.f, 0.f};
  #pragma unroll
  for (int a = 0; a < 4; ++a)
    #pragma unroll
    for (int b = 0; b < 4; ++b) acc[a][b] = zero4;
  int sr = TID >> 1, sh = (TID & 1) * 32;          // staging: row, k-half
  for (int k0 = 0; k0 < K; k0 += 64) {
    float4 av[8];
    #pragma unroll
    for (int j = 0; j < 8; ++j) av[j] = a_load4<MODE>(A, r0 + sr, k0 + sh + 4 * j, K, Np, p);
    s16x8 bv[4];
    const unsigned short* bsrc = BT + (long)(colB + sr) * K + k0 + sh;
    #pragma unroll
    for (int j = 0; j < 4; ++j) bv[j] = *(const s16x8*)(bsrc + 8 * j);
    __syncthreads();
    unsigned short* ar = As + sr * 72 + sh;
    #pragma unroll
    for (int j = 0; j < 8; ++j) {
      unsigned long long w =
        (unsigned long long)f2bf(av[j].x) | ((unsigned long long)f2bf(av[j].y) << 16) |
        ((unsigned long long)f2bf(av[j].z) << 32) | ((unsigned long long)f2bf(av[j].w) << 48);
      *(unsigned long long*)(ar + 4 * j) = w;
    }
    unsigned short* brr = Bs + sr * 72 + sh;
    #pragma unroll
    for (int j = 0; j < 4; ++j) *(s16x8*)(brr + 8 * j) = bv[j];
    __syncthreads();
    #pragma unroll
    for (int kk = 0; kk < 2; ++kk) {
      int kb = kk * 32 + l4 * 8;
      s16x8 af[4], bfr[4];
      #pragma unroll
      for (int mf = 0; mf < 4; ++mf) af[mf] = *(s16x8*)(As + (wr + mf * 16 + l15) * 72 + kb);
      #pragma unroll
      for (int nf = 0; nf < 4; ++nf) bfr[nf] = *(s16x8*)(Bs + (wc + nf * 16 + l15) * 72 + kb);
      #pragma unroll
      for (int mf = 0; mf < 4; ++mf)
        #pragma unroll
        for (int nf = 0; nf < 4; ++nf)
          acc[mf][nf] = __builtin_amdgcn_mfma_f32_16x16x32_bf16(af[mf], bfr[nf], acc[mf][nf], 0, 0, 0);
    }
  }
  // C/D layout: col = lane&15, row = (lane>>4)*4 + reg
  #pragma unroll
  for (int nf = 0; nf < 4; ++nf) {
    int col = colB + wc + nf * 16 + l15;
    float bb = bias ? bias[col] : 0.f;
    #pragma unroll
    for (int mf = 0; mf < 4; ++mf) {
      #pragma unroll
      for (int rg = 0; rg < 4; ++rg) {
        int row = r0 + wr + mf * 16 + l4 * 4 + rg;
        float v = acc[mf][nf][rg] + bb;
        if (OUTB == 1) {
          ((unsigned short*)Cv)[(long)row * ldc + col] = f2bf(v);
        } else if (OUTB == 2) {
          int bnr = row / Np; int np_ = row - bnr * Np;
          ((unsigned short*)Cv)[((long)bnr * 128 + col) * ldc + np_] = f2bf(v);
        } else {
          ((float*)Cv)[(long)row * ldc + col] = v;
        }
      }
    }
  }
}

// ---------------------------------------------------------------- build transposed bf16 weights
// 7 entries/branch: wql, lv, gq, gk, gv, proj, conv. BT[n*K + k] = bf16(src[k*N + n]).
__global__ __launch_bounds__(256) void makebt_k(const float* __restrict__ Wql, const float* __restrict__ lqkv_w,
                                                const float* __restrict__ g0, const float* __restrict__ g1,
                                                const float* __restrict__ g2, const float* __restrict__ g3,
                                                const float* __restrict__ proj_w,
                                                const float* __restrict__ c0, const float* __restrict__ c1w,
                                                const float* __restrict__ c2, const float* __restrict__ c3,
                                                unsigned short* __restrict__ dst) {
  int ent = blockIdx.y; int i = ent / 7, e = ent - i * 7;
  const int PS[4] = {2, 4, 6, 8};
  const long BOFF[4] = {0, 180224, 491520, 933888};   // 16384*(3+4p) cumsum
  int p = PS[i];
  const float* gw = (i == 0) ? g0 : (i == 1) ? g1 : (i == 2) ? g2 : g3;
  const float* cw = (i == 0) ? c0 : (i == 1) ? c1w : (i == 2) ? c2 : c3;
  const float* src; int K, N; long doff = BOFF[i];
  if (e == 0)      { src = Wql + (long)i * 16384;              K = 128;     N = 128; }
  else if (e == 1) { src = lqkv_w + (long)(i * 3 + 2) * 16384; K = 128;     N = 128; doff += 16384; }
  else if (e <= 4) { src = gw + (long)(e - 2) * p * 16384;     K = p * 128; N = 128; doff += 32768 + (long)(e - 2) * p * 16384; }
  else if (e == 5) { src = proj_w + (long)i * 16384;           K = 128;     N = 128; doff += 32768 + 3L * p * 16384; }
  else             { src = cw;                                 K = 128;     N = 128 * p; doff += 49152 + 3L * p * 16384; }
  long tot = (long)K * N;
  long idx = (long)blockIdx.x * 256 + TID;
  if (idx >= tot) return;
  int n = (int)(idx / K), k = (int)(idx - (long)n * K);
  dst[doff + idx] = f2bf(src[(long)k * N + n]);
}

// ---------------------------------------------------------------- router: cat3 GEMM + gating + top3
__global__ __launch_bounds__(256) void router_k(const float* __restrict__ zf, const float* __restrict__ z_rem,
                                                const float* __restrict__ z_trend,
                                                const float* __restrict__ Wf, const float* __restrict__ bf,
                                                const float* __restrict__ nfeat, const float* __restrict__ nlog,
                                                const float* __restrict__ Wr, const float* __restrict__ br,
                                                const float* __restrict__ Wn, const float* __restrict__ bnb,
                                                float* __restrict__ sparse) {
  __shared__ float As[16][68];
  __shared__ float Bs[16][128];
  __shared__ float Cs[64][132];
  __shared__ float wrn[128][8];
  __shared__ float lrow[64][4];
  long r0 = (long)blockIdx.x * 64;
  float acc[8][4] = {{0}};
  int am = TID >> 2, ak = (TID & 3) * 4;
  int bk = TID >> 4, bc = (TID & 15) * 8;
  int tc = TID & 31, tr = TID >> 5;
  for (int k0 = 0; k0 < 384; k0 += 16) {
    int k = k0 + ak;
    long row = (r0 + am) * 128;
    float4 av;
    if (k < 128) {
      av = *(const float4*)(zf + row + k);
    } else if (k < 256) {
      float4 a = *(const float4*)(zf + row + (k - 128));
      float4 b = *(const float4*)(z_rem + row + (k - 128));
      av = make_float4(a.x - b.x, a.y - b.y, a.z - b.z, a.w - b.w);
    } else {
      av = *(const float4*)(z_trend + row + (k - 256));
    }
    float4 b0 = *(const float4*)(Wf + (long)(k0 + bk) * 128 + bc);
    float4 b1 = *(const float4*)(Wf + (long)(k0 + bk) * 128 + bc + 4);
    __syncthreads();
    As[ak + 0][am] = av.x; As[ak + 1][am] = av.y; As[ak + 2][am] = av.z; As[ak + 3][am] = av.w;
    *(float4*)&Bs[bk][bc] = b0; *(float4*)&Bs[bk][bc + 4] = b1;
    __syncthreads();
    #pragma unroll
    for (int kk = 0; kk < 16; ++kk) {
      float4 bv = *(float4*)&Bs[kk][tc * 4];
      float4 a0 = *(float4*)&As[kk][tr * 8];
      float4 a1 = *(float4*)&As[kk][tr * 8 + 4];
      FMA_ROW(0, a0.x) FMA_ROW(1, a0.y) FMA_ROW(2, a0.z) FMA_ROW(3, a0.w)
      FMA_ROW(4, a1.x) FMA_ROW(5, a1.y) FMA_ROW(6, a1.z) FMA_ROW(7, a1.w)
    }
  }
  for (int idx = TID; idx < 128; idx += 256) {
    #pragma unroll
    for (int c = 0; c < 4; ++c) { wrn[idx][c] = Wr[idx * 4 + c]; wrn[idx][4 + c] = Wn[idx * 4 + c]; }
  }
  #pragma unroll
  for (int i = 0; i < 8; ++i) {
    long r = r0 + tr * 8 + i;
    float4 nfv = *(const float4*)(nfeat + r * 128 + tc * 4);
    Cs[tr * 8 + i][tc * 4 + 0] = acc[i][0] + bf[tc * 4 + 0] + 0.1f * nfv.x;
    Cs[tr * 8 + i][tc * 4 + 1] = acc[i][1] + bf[tc * 4 + 1] + 0.1f * nfv.y;
    Cs[tr * 8 + i][tc * 4 + 2] = acc[i][2] + bf[tc * 4 + 2] + 0.1f * nfv.z;
    Cs[tr * 8 + i][tc * 4 + 3] = acc[i][3] + bf[tc * 4 + 3] + 0.1f * nfv.w;
  }
  __syncthreads();
  int rr = TID >> 2, c = TID & 3;
  float la = 0.f, lb2 = 0.f;
  for (int d = 0; d < 128; ++d) {
    float g = Cs[rr][d];
    la += g * wrn[d][c]; lb2 += g * wrn[d][4 + c];
  }
  long r = r0 + rr;
  float x = lb2 + bnb[c];
  float sp = (x > 0.f) ? x + log1pf(expf(-x)) : log1pf(expf(x));
  float lg = la + br[c] + nlog[r * 4 + c] * sp;
  lrow[rr][c] = lg;
  __syncthreads();
  float l0 = lrow[rr][0], l1 = lrow[rr][1], l2 = lrow[rr][2], l3 = lrow[rr][3];
  float mx = fmaxf(fmaxf(l0, l1), fmaxf(l2, l3));
  float e0 = expf(l0 - mx), e1 = expf(l1 - mx), e2 = expf(l2 - mx), e3 = expf(l3 - mx);
  float s = e0 + e1 + e2 + e3;
  float r0v = e0 / s, r1v = e1 / s, r2v = e2 / s, r3v = e3 / s;
  int zi = 0; float mv = r0v;
  if (r1v <= mv) { mv = r1v; zi = 1; }
  if (r2v <= mv) { mv = r2v; zi = 2; }
  if (r3v <= mv) { mv = r3v; zi = 3; }
  float rwc = (c == 0) ? r0v : (c == 1) ? r1v : (c == 2) ? r2v : r3v;
  sparse[r * 4 + c] = (c == zi) ? 0.f : rwc;
}

// ---------------------------------------------------------------- per-branch combined local-attn weights
__global__ __launch_bounds__(256) void precompute_k(const float* __restrict__ lqkv_w,
                                                    const float* __restrict__ lqkv_b,
                                                    float* __restrict__ Wql, float* __restrict__ bql,
                                                    float* __restrict__ v1, float* __restrict__ c1) {
  int i = blockIdx.x;
  const float* lw0 = lqkv_w + (long)(i * 3 + 0) * 16384;
  const float* lw1 = lqkv_w + (long)(i * 3 + 1) * 16384;
  const float* lb0 = lqkv_b + (i * 3 + 0) * 128;
  const float* lb1 = lqkv_b + (i * 3 + 1) * 128;
  for (int idx = TID; idx < 16384; idx += 256) {
    int dp = idx >> 7, d = idx & 127;
    float s = 0.f;
    for (int e = 0; e < 128; ++e) s += lw0[dp * 128 + e] * lw1[d * 128 + e];
    Wql[(long)i * 16384 + idx] = s;
  }
  for (int d = TID; d < 128; d += 256) {
    float s = 0.f, s2 = 0.f;
    for (int e = 0; e < 128; ++e) { s += lb0[e] * lw1[d * 128 + e]; s2 += lw0[d * 128 + e] * lb1[e]; }
    bql[i * 128 + d] = s;
    v1[i * 128 + d] = s2;
  }
  if (TID == 0) {
    float s = 0.f;
    for (int e = 0; e < 128; ++e) s += lb0[e] * lb1[e];
    c1[i] = s;
  }
}

// ---------------------------------------------------------------- local attention -> pooled patches
__global__ __launch_bounds__(256) void local_attn(const float* __restrict__ zf, const float* __restrict__ w_vec,
                                                  const float* __restrict__ v1, const float* __restrict__ c1,
                                                  float* __restrict__ pooled, int Np, int p, int ibr) {
  int lane = TID & 63, wid = TID >> 6;
  int r = blockIdx.x * 4 + wid;
  int bn = r / Np, np_ = r - bn * Np;
  int d0 = lane, d1 = lane + 64;
  float wv0 = w_vec[(long)r * 128 + d0];
  float wv1 = w_vec[(long)r * 128 + d1];
  float p0[8], p1[8], sj[8];
  #pragma unroll
  for (int j = 0; j < 8; ++j) {
    p0[j] = 0.f; p1[j] = 0.f;
    if (j < p) {
      int t = np_ * p + j;
      if (t < Tn) {
        const float* src = zf + ((long)bn * Tn + t) * Dn;
        p0[j] = src[d0]; p1[j] = src[d1];
      }
    }
    float v = wv0 * p0[j] + wv1 * p1[j];
    sj[j] = wave_sum(v);
  }
  float pm0 = 0.f, pm1 = 0.f;
  #pragma unroll
  for (int j = 0; j < 8; ++j) if (j < p) { pm0 += p0[j]; pm1 += p1[j]; }
  float invp = 1.f / (float)p;
  pm0 *= invp; pm1 *= invp;
  float qb = wave_sum(pm0 * v1[ibr * 128 + d0] + pm1 * v1[ibr * 128 + d1]) + c1[ibr];
  const float scale = 0.08838834764831845f;
  float mx = -1e30f;
  #pragma unroll
  for (int j = 0; j < 8; ++j) if (j < p) { sj[j] = (sj[j] + qb) * scale; mx = fmaxf(mx, sj[j]); }
  float se = 0.f; float ej[8];
  #pragma unroll
  for (int j = 0; j < 8; ++j) { ej[j] = 0.f; if (j < p) { ej[j] = expf(sj[j] - mx); se += ej[j]; } }
  float inv = 1.f / se;
  float o0 = 0.f, o1 = 0.f;
  #pragma unroll
  for (int j = 0; j < 8; ++j) if (j < p) { float w = ej[j] * inv; o0 += w * p0[j]; o1 += w * p1[j]; }
  pooled[(long)r * 128 + d0] = o0;
  pooled[(long)r * 128 + d1] = o1;
}

// ---------------------------------------------------------------- MFMA global sigmoid-softmax attention (lo +=)
// Per block: one bn, 64 q-rows; 4 waves, wave w owns q-rows [q0+16w, q0+16w+16).
// Q,K fragments load straight from global (bf16 row-major); V from gvT (bf16, [bn][d][n], ldc=NpT).
__global__ __launch_bounds__(256) void gattn_m(const unsigned short* __restrict__ gq,
                                               const unsigned short* __restrict__ gk,
                                               const unsigned short* __restrict__ gvT,
                                               float* __restrict__ lo, int Np, int NpT) {
  int bn = blockIdx.y;
  int q0 = blockIdx.x * 64;
  int wid = TID >> 6, lane = TID & 63;
  int l15 = lane & 15, l4 = lane >> 4;
  __shared__ __align__(16) unsigned short Wl[4][16][40];   // 80B row stride: 16B-aligned, 2-way max
  const float scale = 0.08838834764831845f;

  int qrow = q0 + 16 * wid + l15;
  const unsigned short* qbase = gq + ((long)bn * Np + min(qrow, Np - 1)) * 128 + l4 * 8;
  s16x8 aq[4];
  #pragma unroll
  for (int c = 0; c < 4; ++c) aq[c] = *(const s16x8*)(qbase + c * 32);

  f32x4 z4 = {0.f, 0.f, 0.f, 0.f};
  f32x4 outa[8];
  #pragma unroll
  for (int dsb = 0; dsb < 8; ++dsb) outa[dsb] = z4;
  float dsum[4] = {0.f, 0.f, 0.f, 0.f};

  int ntiles = (Np + 31) >> 5;
  for (int nt = 0; nt < ntiles; ++nt) {
    int n0 = nt * 32;
    f32x4 sacc[2];
    sacc[0] = z4; sacc[1] = z4;
    #pragma unroll
    for (int st = 0; st < 2; ++st) {
      int nrow = n0 + st * 16 + l15;
      const unsigned short* kbase = gk + ((long)bn * Np + min(nrow, Np - 1)) * 128 + l4 * 8;
      #pragma unroll
      for (int c = 0; c < 4; ++c) {
        s16x8 bk = *(const s16x8*)(kbase + c * 32);
        sacc[st] = __builtin_amdgcn_mfma_f32_16x16x32_bf16(aq[c], bk, sacc[st], 0, 0, 0);
      }
    }
    // w = exp(sigmoid(s)*scale); 0 where n >= Np. Lane holds (m=l4*4+r, n=n0+st*16+l15).
    #pragma unroll
    for (int st = 0; st < 2; ++st) {
      int n = n0 + st * 16 + l15;
      bool ok = (n < Np);
      #pragma unroll
      for (int r = 0; r < 4; ++r) {
        float s = sacc[st][r];
        float sg = __builtin_amdgcn_rcpf(1.f + __expf(-s));
        float w = ok ? __expf(scale * sg) : 0.f;
        unsigned short wb = f2bf(w);
        dsum[r] += ok ? bf2f(wb) : 0.f;                 // denom matches bf16 numerator
        Wl[wid][l4 * 4 + r][st * 16 + l15] = wb;
      }
    }
    // repack W (C-layout) -> A-fragment via wave-local LDS (no barrier: same-wave in-order DS)
    s16x8 aw = *(s16x8*)&Wl[wid][l15][l4 * 8];
    const unsigned short* vbase = gvT + ((long)bn * 128 + l15) * NpT + n0 + l4 * 8;
    #pragma unroll
    for (int dsb = 0; dsb < 8; ++dsb) {
      s16x8 bv = *(const s16x8*)(vbase + (long)dsb * 16 * NpT);
      outa[dsb] = __builtin_amdgcn_mfma_f32_16x16x32_bf16(aw, bv, outa[dsb], 0, 0, 0);
    }
  }
  float inv[4];
  #pragma unroll
  for (int r = 0; r < 4; ++r) {
    float v = dsum[r];
    v += __shfl_xor(v, 1); v += __shfl_xor(v, 2); v += __shfl_xor(v, 4); v += __shfl_xor(v, 8);
    inv[r] = 1.f / v;
  }
  #pragma unroll
  for (int r = 0; r < 4; ++r) {
    int m = q0 + 16 * wid + l4 * 4 + r;
    if (m < Np) {
      float* lp = lo + ((long)bn * Np + m) * 128 + l15;
      #pragma unroll
      for (int dsb = 0; dsb < 8; ++dsb) lp[dsb * 16] += outa[dsb][r] * inv[r];
    }
  }
}

// ---------------------------------------------------------------- convT scatter + gate, DIRECT to out
__global__ __launch_bounds__(256) void scatter2_k(const float* __restrict__ up_t, const float* __restrict__ sparse,
                                                  const float* __restrict__ cb, float* __restrict__ out,
                                                  int Np, int p, int ibr) {
  int bn = blockIdx.x; int t0 = blockIdx.y * 128; int o0 = blockIdx.z * 16;
  __shared__ float tile[16][132];
  int np0 = t0 / p;
  int np1 = (t0 + 127) / p;
  if (np1 > Np - 1) np1 = Np - 1;
  int per = 16 * p;
  int npi = 256 / per;
  int sub = TID / per;
  int e   = TID - sub * per;
  int ol = e / p, j = e - ol * p;
  for (int npb = np0; npb <= np1; npb += npi) {
    int np_ = npb + sub;
    if (sub < npi && np_ <= np1) {
      int t = np_ * p + j;
      if (t >= t0 && t < t0 + 128 && t < Tn) {
        tile[ol][t - t0] = up_t[(((long)bn * Np + np_) * 128 + o0 + ol) * (long)p + j];
      }
    }
  }
  __syncthreads();
  int dd = TID & 127, ow = TID >> 7;
  int t = t0 + dd;
  float sp = sparse[((long)bn * 1024 + t) * 4 + ibr];
  int b = bn >> 5, n = bn & 31;
  int thi = t0 >> 7;
  for (int ol2 = ow; ol2 < 16; ol2 += 2) {
    int o = o0 + ol2;
    float v = sp * (tile[ol2][dd] + cb[o]);
    long idx = (((long)b * 1024 + o * 8 + thi) * 32 + n) * 128 + dd;
    out[idx] += v;
  }
}

// ---------------------------------------------------------------- launch
extern "C" void kernel_launch(void* const* d_in, const int* in_sizes, int n_in,
                              void* d_out, int out_size, void* d_ws, size_t ws_size,
                              hipStream_t stream) {
  const float* z      = (const float*)d_in[0];
  const float* nfeat  = (const float*)d_in[1];
  const float* nlog   = (const float*)d_in[2];
  const float* Wq_tr  = (const float*)d_in[3];
  const float* bq_tr  = (const float*)d_in[4];
  const float* Wf     = (const float*)d_in[5];
  const float* bf     = (const float*)d_in[6];
  const float* Wr     = (const float*)d_in[7];
  const float* br     = (const float*)d_in[8];
  const float* Wn     = (const float*)d_in[9];
  const float* bnb    = (const float*)d_in[10];
  const float* lqkv_w = (const float*)d_in[11];
  const float* lqkv_b = (const float*)d_in[12];
  const float* gqkvb  = (const float*)d_in[13];
  const float* proj_w = (const float*)d_in[14];
  const float* proj_b = (const float*)d_in[15];
  const float* conv_b = (const float*)d_in[16];
  const float* gqkv_w[4] = {(const float*)d_in[17], (const float*)d_in[19],
                            (const float*)d_in[21], (const float*)d_in[23]};
  const float* conv_w[4] = {(const float*)d_in[18], (const float*)d_in[20],
                            (const float*)d_in[22], (const float*)d_in[24]};
  float* out = (float*)d_out;
  float* ws = (float*)d_ws;

  // ---- workspace layout (floats)
  float* zf     = ws;                         // 2*SL (persistent)
  float* LOOP   = ws + 2 * SL;                // 4*SL (phase-aliased)
  float* sparse = ws + 6 * SL;                // 1,048,576
  int*   keyf   = (int*)(sparse + 1048576);   // 32,768 ints
  float* amp_re = sparse + 1048576 + 65536;   // 32,768
  float* amp_im = amp_re + 32768;             // 32,768
  float* alpha  = amp_im + 32768;             // 1,024
  float* Wql    = alpha + 1024;               // 65,536
  float* bql    = Wql + 65536;                // 512
  float* v1     = bql + 512;                  // 512
  float* c1     = v1 + 512;                   // 64
  // BT bf16 table in second half of s3; gvT (bf16, <= SL/2 floats) in first half of s3.
  unsigned short* BT = (unsigned short*)(ws + 5 * SL + SL / 2);   // 1,507,328 shorts

  // pre-phase aliases inside LOOP
  float* z_rem   = LOOP;                      // 2 SL
  float* z_trend = LOOP + 2 * SL;             // 2 SL

  hipMemsetAsync(out, 0, (size_t)out_size * sizeof(float), stream);

  transpose_k<<<32768, 256, 0, stream>>>(z, zf);
  fft_k<<<dim3(256, 32), 256, 0, stream>>>(zf, keyf, amp_re, amp_im);
  zrem_k<<<32768, 256, 0, stream>>>(zf, keyf, amp_re, amp_im, z_rem);
  alpha_k<<<256, 256, 0, stream>>>(z_rem, Wq_tr, bq_tr, alpha);
  trend_k<<<32768, 256, 0, stream>>>(z_rem, alpha, z_trend);
  router_k<<<4096, 256, 0, stream>>>(zf, z_rem, z_trend, Wf, bf, nfeat, nlog, Wr, br, Wn, bnb, sparse);
  precompute_k<<<4, 256, 0, stream>>>(lqkv_w, lqkv_b, Wql, bql, v1, c1);
  makebt_k<<<dim3(512, 28), 256, 0, stream>>>(Wql, lqkv_w, gqkv_w[0], gqkv_w[1], gqkv_w[2], gqkv_w[3],
                                              proj_w, conv_w[0], conv_w[1], conv_w[2], conv_w[3], BT);

  const int PS[4]   = {2, 4, 6, 8};
  const int NPs[4]  = {512, 256, 171, 128};
  const int NPTs[4] = {512, 256, 192, 128};   // ceil32(Np) so PV k-range stays in-row
  const long BOFF[4] = {0, 180224, 491520, 933888};
  for (int i = 0; i < 4; ++i) {
    int p = PS[i], Np = NPs[i], NpT = NPTs[i];
    int M = BNn * Np;
    float* w_vec  = LOOP + 0 * SL;
    float* pooled = LOOP + 1 * SL;
    float* lob    = LOOP + 2 * SL;
    unsigned short* gqb = (unsigned short*)(LOOP + 0 * SL);
    unsigned short* gkb = (unsigned short*)(LOOP + 1 * SL);
    unsigned short* gvT = (unsigned short*)(LOOP + 3 * SL);
    float* fusedb = LOOP + 0 * SL;
    float* up_t   = LOOP + 1 * SL;

    long bo = BOFF[i];
    const unsigned short* bt_wql  = BT + bo;
    const unsigned short* bt_lv   = BT + bo + 16384;
    const unsigned short* bt_g0   = BT + bo + 32768;
    const unsigned short* bt_g1   = bt_g0 + (long)p * 16384;
    const unsigned short* bt_g2   = bt_g1 + (long)p * 16384;
    const unsigned short* bt_proj = bt_g0 + 3L * p * 16384;
    const unsigned short* bt_conv = bt_proj + 16384;

    mgemm_k<GM_PMEAN, 0><<<dim3(M / 128, 1), 256, 0, stream>>>(zf, bt_wql, bql + i * 128,
                                                               w_vec, M, 128, 128, Np, p);
    local_attn<<<M / 4, 256, 0, stream>>>(zf, w_vec, v1, c1, pooled, Np, p, i);
    mgemm_k<GM_PLAIN, 0><<<dim3(M / 128, 1), 256, 0, stream>>>(pooled, bt_lv, lqkv_b + (i * 3 + 2) * 128,
                                                               lob, M, 128, 128, Np, p);
    mgemm_k<GM_FLAT, 1><<<dim3(M / 128, 1), 256, 0, stream>>>(zf, bt_g0, gqkvb + (i * 3 + 0) * 128,
                                                              gqb, M, p * 128, 128, Np, p);
    mgemm_k<GM_FLAT, 1><<<dim3(M / 128, 1), 256, 0, stream>>>(zf, bt_g1, gqkvb + (i * 3 + 1) * 128,
                                                              gkb, M, p * 128, 128, Np, p);
    if (NpT != Np)   // p=6: zero pad cols so 0*garbage can't be NaN in PV
      hipMemsetAsync((void*)gvT, 0, (size_t)256 * 128 * NpT * 2, stream);
    mgemm_k<GM_FLAT, 2><<<dim3(M / 128, 1), 256, 0, stream>>>(zf, bt_g2, gqkvb + (i * 3 + 2) * 128,
                                                              gvT, M, p * 128, NpT, Np, p);
    gattn_m<<<dim3((Np + 63) / 64, 256), 256, 0, stream>>>(gqb, gkb, gvT, lob, Np, NpT);
    mgemm_k<GM_PLAIN, 0><<<dim3(M / 128, 1), 256, 0, stream>>>(lob, bt_proj, proj_b + i * 128,
                                                               fusedb, M, 128, 128, Np, p);
    mgemm_k<GM_PLAIN, 0><<<dim3(M / 128, p), 256, 0, stream>>>(fusedb, bt_conv, nullptr, up_t,
                                                               M, 128, 128 * p, Np, p);
    scatter2_k<<<dim3(256, 8, 8), 256, 0, stream>>>(up_t, sparse, conv_b + i * 128, out, Np, p, i);
  }
}